// Round 2
// baseline (3330.993 us; speedup 1.0000x reference)
//
#include <hip/hip_runtime.h>
#include <hip/hip_bf16.h>
#include <hip/hip_fp16.h>

#define D_MODEL 768
#define NHEADS  12
#define HD      64
#define BATCH   2
#define SEQ     2048
#define NTOK    (BATCH*SEQ)   // 4096

typedef __attribute__((ext_vector_type(8))) short short8;
typedef __attribute__((ext_vector_type(4))) float f32x4;

__device__ __forceinline__ float bf2f(short s) {
    union { unsigned u; float f; } c;
    c.u = ((unsigned)(unsigned short)s) << 16;
    return c.f;
}
__device__ __forceinline__ short f2bf(float f) {
    __hip_bfloat16 h = __float2bfloat16(f);
    return *(short*)&h;
}

// ---------------------------------------------------------------------------
// Dtype detector: scan first 4096 halfwords of x. If inputs are fp32, the
// mantissa halfwords have uniform random bf16-exponent fields -> some >140
// with overwhelming probability. bf16(N(0,1)) data has exponent <= ~130.
// flag: 1 = inputs are fp32, 0 = inputs are bf16.
// ---------------------------------------------------------------------------
__global__ void detect_dtype(const short* __restrict__ x, int* __restrict__ flag) {
    __shared__ int red[256];
    const int tid = threadIdx.x;
    int maxe = 0;
    for (int i = tid; i < 4096; i += 256) {
        int e = ((unsigned short)x[i] >> 7) & 0xFF;
        maxe = max(maxe, e);
    }
    red[tid] = maxe;
    __syncthreads();
    for (int s = 128; s > 0; s >>= 1) {
        if (tid < s) red[tid] = max(red[tid], red[tid + s]);
        __syncthreads();
    }
    if (tid == 0) *flag = (red[0] > 140) ? 1 : 0;
}

// Canonicalize any input buffer to bf16 in workspace.
__global__ void convert_to_bf16(const void* __restrict__ src, short* __restrict__ dst,
                                int n, const int* __restrict__ flag) {
    int i = blockIdx.x * blockDim.x + threadIdx.x;
    const int stride = gridDim.x * blockDim.x;
    if (*flag) {
        const float* s = (const float*)src;
        for (; i < n; i += stride) dst[i] = f2bf(s[i]);
    } else {
        const short* s = (const short*)src;
        for (; i < n; i += stride) dst[i] = s[i];
    }
}

// ---------------------------------------------------------------------------
// GEMM: out[4096][768] = X[4096][768](bf16) @ W[768][768](bf16) + bias(bf16)
// Block 256 thr; block tile 64x64; wave tile 16(M) x 64(N), 4 mfma 16x16x32.
// Layouts (learn_hip-verified): A[m=lane&15][k=quad*8+j],
// B[k=quad*8+j][n=lane&15], D: col=lane&15, row=quad*4+reg.
// OMODE 0: bf16 store to ws. OMODE 1: final output, dtype chosen by *flag.
// ---------------------------------------------------------------------------
template<int OMODE>
__global__ __launch_bounds__(256) void proj_gemm(const short* __restrict__ X,
                                                 const short* __restrict__ W,
                                                 const short* __restrict__ bias,
                                                 void* __restrict__ out,
                                                 const int* __restrict__ flag)
{
    const int lane = threadIdx.x & 63;
    const int wave = threadIdx.x >> 6;
    const int quad = lane >> 4;
    const int l16  = lane & 15;
    const int m0 = blockIdx.x * 64 + wave * 16;
    const int n0 = blockIdx.y * 64;

    f32x4 acc[4];
#pragma unroll
    for (int t = 0; t < 4; ++t) {
        float bv = bf2f(bias[n0 + t*16 + l16]);
        acc[t] = (f32x4){bv, bv, bv, bv};
    }

    const short* xrow = X + (size_t)(m0 + l16) * D_MODEL;
    for (int k0 = 0; k0 < D_MODEL; k0 += 32) {
        short8 a = *(const short8*)(xrow + k0 + quad*8);
#pragma unroll
        for (int t = 0; t < 4; ++t) {
            const short* wp = W + (size_t)(k0 + quad*8) * D_MODEL + n0 + t*16 + l16;
            short8 bfr;
#pragma unroll
            for (int j = 0; j < 8; ++j) bfr[j] = wp[(size_t)j * D_MODEL];
            acc[t] = __builtin_amdgcn_mfma_f32_16x16x32_bf16(a, bfr, acc[t], 0, 0, 0);
        }
    }

    const bool outf32 = (OMODE == 1) && (*flag != 0);
#pragma unroll
    for (int t = 0; t < 4; ++t) {
        const int n = n0 + t*16 + l16;
#pragma unroll
        for (int r = 0; r < 4; ++r) {
            const int m = m0 + quad*4 + r;
            const size_t idx = (size_t)m * D_MODEL + n;
            if (OMODE == 0)      ((short*)out)[idx] = f2bf(acc[t][r]);
            else if (outf32)     ((float*)out)[idx] = acc[t][r];
            else                 ((short*)out)[idx] = f2bf(acc[t][r]);
        }
    }
}

// ---------------------------------------------------------------------------
// Attention (fp32 vector ALU): block = (b,h) x 8 query rows.
// Phase A: logits -> LDS fp16. Phase B: softmax (fp32 reductions),
// unnormalized fp16 probs. Phase C: PV accumulate fp32, normalize, bf16 out.
// LDS ~36 KB.
// ---------------------------------------------------------------------------
__global__ __launch_bounds__(256) void attn_fp32(const short* __restrict__ q,
                                                 const short* __restrict__ k,
                                                 const short* __restrict__ v,
                                                 short* __restrict__ ctx)
{
    __shared__ float  qs[8][HD];      // 2 KB (pre-scaled by 1/8)
    __shared__ __half sc[8][SEQ];     // 32 KB
    __shared__ float  red[8][32];     // 1 KB
    __shared__ float  rowinv[8];

    const int b  = blockIdx.y / NHEADS;
    const int h  = blockIdx.y % NHEADS;
    const int q0 = blockIdx.x * 8;
    const int tid = threadIdx.x;

    for (int e = tid; e < 8*HD; e += 256) {
        const int i = e >> 6, d = e & 63;
        qs[i][d] = bf2f(q[(size_t)(b*SEQ + q0 + i) * D_MODEL + h*HD + d]) * 0.125f;
    }
    __syncthreads();

    // ---- Phase A: logits ----
    for (int jc = 0; jc < SEQ/256; ++jc) {
        const int j = jc*256 + tid;
        const short8* kp = (const short8*)(k + (size_t)(b*SEQ + j) * D_MODEL + h*HD);
        float kr[HD];
#pragma unroll
        for (int u = 0; u < 8; ++u) {
            short8 kv = kp[u];
#pragma unroll
            for (int t = 0; t < 8; ++t) kr[8*u+t] = bf2f(kv[t]);
        }
#pragma unroll
        for (int i = 0; i < 8; ++i) {
            const float4* qp = (const float4*)qs[i];   // wave-uniform -> LDS broadcast
            float s = 0.f;
#pragma unroll
            for (int u = 0; u < 16; ++u) {
                float4 qf = qp[u];
                s += qf.x*kr[4*u] + qf.y*kr[4*u+1] + qf.z*kr[4*u+2] + qf.w*kr[4*u+3];
            }
            sc[i][j] = __float2half(s);
        }
    }
    __syncthreads();

    // ---- Phase B: softmax (unnormalized; keep 1/rowsum) ----
    {
        const int i  = tid >> 5;   // 8 rows x 32 threads
        const int tl = tid & 31;
        float m = -1e30f;
        for (int c = 0; c < SEQ/32; ++c) m = fmaxf(m, __half2float(sc[i][tl + 32*c]));
        red[i][tl] = m;
        __syncthreads();
        float rm = -1e30f;
        for (int c = 0; c < 32; ++c) rm = fmaxf(rm, red[i][c]);
        __syncthreads();
        float sum = 0.f;
        for (int c = 0; c < SEQ/32; ++c) {
            const int j = tl + 32*c;
            const float p = __expf(__half2float(sc[i][j]) - rm);
            sum += p;
            sc[i][j] = __float2half(p);
        }
        red[i][tl] = sum;
        __syncthreads();
        if (tl == 0) {
            float rs = 0.f;
            for (int c = 0; c < 32; ++c) rs += red[i][c];
            rowinv[i] = 1.0f / rs;
        }
    }
    __syncthreads();

    // ---- Phase C: ctx = P @ V ----
    {
        const int d  = tid & 63;
        const int ig = tid >> 6;   // rows ig and ig+4
        const short* vb = v + (size_t)(b*SEQ) * D_MODEL + h*HD + d;
        float a0 = 0.f, a1 = 0.f;
        for (int j = 0; j < SEQ; j += 2) {
            const float2 p0 = __half22float2(*(const __half2*)&sc[ig][j]);
            const float2 p1 = __half22float2(*(const __half2*)&sc[ig+4][j]);
            const float v0 = bf2f(vb[(size_t)j * D_MODEL]);       // coalesced
            const float v1 = bf2f(vb[(size_t)(j+1) * D_MODEL]);
            a0 += p0.x*v0 + p0.y*v1;
            a1 += p1.x*v0 + p1.y*v1;
        }
        a0 *= rowinv[ig];
        a1 *= rowinv[ig+4];
        ctx[(size_t)(b*SEQ + q0 + ig  ) * D_MODEL + h*HD + d] = f2bf(a0);
        ctx[(size_t)(b*SEQ + q0 + ig+4) * D_MODEL + h*HD + d] = f2bf(a1);
    }
}

// ---------------------------------------------------------------------------
extern "C" void kernel_launch(void* const* d_in, const int* in_sizes, int n_in,
                              void* d_out, int out_size, void* d_ws, size_t ws_size,
                              hipStream_t stream)
{
    // ws layout: [0..64) flag header; then bf16 segments.
    int* flag = (int*)d_ws;
    short* base = (short*)((char*)d_ws + 64);
    const size_t NX = (size_t)NTOK * D_MODEL;   // 3,145,728
    const size_t NW = (size_t)D_MODEL * D_MODEL;// 589,824
    short* xc  = base;
    short* Wqc = xc  + NX;
    short* Wkc = Wqc + NW;
    short* Wvc = Wkc + NW;
    short* Woc = Wvc + NW;
    short* bqc = Woc + NW;
    short* bkc = bqc + D_MODEL;
    short* bvc = bkc + D_MODEL;
    short* boc = bvc + D_MODEL;
    short* qb  = boc + D_MODEL;
    short* kb  = qb  + NX;
    short* vb  = kb  + NX;
    short* cb  = vb  + NX;

    detect_dtype<<<1, 256, 0, stream>>>((const short*)d_in[0], flag);

    auto conv = [&](int i, short* dst, int n) {
        convert_to_bf16<<<(n + 1023)/1024, 256, 0, stream>>>(d_in[i], dst, n, flag);
    };
    conv(0, xc,  (int)NX);
    conv(1, Wqc, (int)NW);
    conv(2, bqc, D_MODEL);
    conv(3, Wkc, (int)NW);
    conv(4, bkc, D_MODEL);
    conv(5, Wvc, (int)NW);
    conv(6, bvc, D_MODEL);
    conv(7, Woc, (int)NW);
    conv(8, boc, D_MODEL);

    dim3 gblk(NTOK/64, D_MODEL/64);   // 64 x 12
    dim3 blk(256);
    proj_gemm<0><<<gblk, blk, 0, stream>>>(xc, Wqc, bqc, qb, flag);
    proj_gemm<0><<<gblk, blk, 0, stream>>>(xc, Wkc, bkc, kb, flag);
    proj_gemm<0><<<gblk, blk, 0, stream>>>(xc, Wvc, bvc, vb, flag);

    attn_fp32<<<dim3(SEQ/8, BATCH*NHEADS), blk, 0, stream>>>(qb, kb, vb, cb);

    proj_gemm<1><<<gblk, blk, 0, stream>>>(cb, Woc, boc, d_out, flag);
}

// Round 3
// 328.080 us; speedup vs baseline: 10.1530x; 10.1530x over previous
//
#include <hip/hip_runtime.h>
#include <hip/hip_bf16.h>
#include <hip/hip_fp16.h>

#define D_MODEL 768
#define NHEADS  12
#define HD      64
#define BATCH   2
#define SEQ     2048
#define NTOK    (BATCH*SEQ)   // 4096
#define NX      ((size_t)NTOK * D_MODEL)     // 3,145,728
#define NW      ((size_t)D_MODEL * D_MODEL)  // 589,824

typedef __attribute__((ext_vector_type(8))) short   short8;
typedef __attribute__((ext_vector_type(8))) _Float16 half8;
typedef __attribute__((ext_vector_type(4))) float   f32x4;

__device__ __forceinline__ float bf2f(short s) {
    union { unsigned u; float f; } c;
    c.u = ((unsigned)(unsigned short)s) << 16;
    return c.f;
}
__device__ __forceinline__ short f2bf(float f) {
    __hip_bfloat16 h = __float2bfloat16(f);
    return *(short*)&h;
}

// ---------------------------------------------------------------------------
// Dtype detector: if inputs are fp32, reading them as bf16 halfwords shows
// exponent fields >140 with overwhelming probability. flag: 1=fp32, 0=bf16.
// ---------------------------------------------------------------------------
__global__ void detect_dtype(const short* __restrict__ x, int* __restrict__ flag) {
    __shared__ int red[256];
    const int tid = threadIdx.x;
    int maxe = 0;
    for (int i = tid; i < 4096; i += 256) {
        int e = ((unsigned short)x[i] >> 7) & 0xFF;
        maxe = max(maxe, e);
    }
    red[tid] = maxe;
    __syncthreads();
    for (int s = 128; s > 0; s >>= 1) {
        if (tid < s) red[tid] = max(red[tid], red[tid + s]);
        __syncthreads();
    }
    if (tid == 0) *flag = (red[0] > 140) ? 1 : 0;
}

// x conversion, 4-wide.
__global__ void conv_x4(const void* __restrict__ src, short* __restrict__ dst,
                        int n4, const int* __restrict__ flag) {
    const int i = blockIdx.x * 256 + threadIdx.x;
    if (i >= n4) return;
    if (*flag) {
        float4 f = ((const float4*)src)[i];
        short4 o = { f2bf(f.x), f2bf(f.y), f2bf(f.z), f2bf(f.w) };
        ((short4*)dst)[i] = o;
    } else {
        ((short4*)dst)[i] = ((const short4*)src)[i];
    }
}

// Fused convert+transpose of the 4 weight matrices: Wt[n][k] = W[k][n], bf16.
__global__ __launch_bounds__(256) void conv_wt(const void* __restrict__ w0,
                                               const void* __restrict__ w1,
                                               const void* __restrict__ w2,
                                               const void* __restrict__ w3,
                                               short* __restrict__ wt,
                                               const int* __restrict__ flag)
{
    __shared__ float T[64][65];
    const int z = blockIdx.z;
    const void* src = (z == 0) ? w0 : (z == 1) ? w1 : (z == 2) ? w2 : w3;
    const int k0 = blockIdx.x * 64, n0 = blockIdx.y * 64;
    const int a = threadIdx.x & 15, b = threadIdx.x >> 4;   // b in 0..15
    const bool isf = (*flag != 0);
#pragma unroll
    for (int u = 0; u < 4; ++u) {
        const int kr = (b & 3) + 4 * u + 16 * (b >> 2);   // 0..63, 16 rows per pass
        if (isf) {
            float4 f = *(const float4*)((const float*)src + (size_t)(k0 + kr) * D_MODEL + n0 + a * 4);
            T[kr][a*4+0] = f.x; T[kr][a*4+1] = f.y; T[kr][a*4+2] = f.z; T[kr][a*4+3] = f.w;
        } else {
            short4 s = *(const short4*)((const short*)src + (size_t)(k0 + kr) * D_MODEL + n0 + a * 4);
            T[kr][a*4+0] = bf2f(s.x); T[kr][a*4+1] = bf2f(s.y); T[kr][a*4+2] = bf2f(s.z); T[kr][a*4+3] = bf2f(s.w);
        }
    }
    __syncthreads();
#pragma unroll
    for (int u = 0; u < 4; ++u) {
        const int nr = (b & 3) + 4 * u + 16 * (b >> 2);
        short4 o = { f2bf(T[a*4+0][nr]), f2bf(T[a*4+1][nr]),
                     f2bf(T[a*4+2][nr]), f2bf(T[a*4+3][nr]) };
        *(short4*)(wt + (size_t)z * NW + (size_t)(n0 + nr) * D_MODEL + k0 + a * 4) = o;
    }
}

// Convert the 4 bias vectors (768 each) to bf16, contiguous.
__global__ void conv_bias(const void* __restrict__ b0, const void* __restrict__ b1,
                          const void* __restrict__ b2, const void* __restrict__ b3,
                          short* __restrict__ dst, const int* __restrict__ flag)
{
    const int tid = threadIdx.x;
    const void* srcs[4] = { b0, b1, b2, b3 };
    const bool isf = (*flag != 0);
    for (int z = 0; z < 4; ++z) {
        for (int i = tid; i < D_MODEL; i += 256) {
            short o = isf ? f2bf(((const float*)srcs[z])[i]) : ((const short*)srcs[z])[i];
            dst[z * D_MODEL + i] = o;
        }
    }
}

// ---------------------------------------------------------------------------
// Projection GEMM, LDS-free: A-frags from X (global b128), B-frags from Wt
// (global b128, L2-resident). Block 256 thr = 4 waves; tile 128(M) x 64(N);
// wave = 32(M) x 64(N): 8 mfma_16x16x32_bf16 per k-step, 24 k-steps.
// OMODE 0: bf16 out. OMODE 1: final out, fp32/bf16 chosen by *flag.
// ---------------------------------------------------------------------------
template<int OMODE>
__global__ __launch_bounds__(256) void proj_gemm(const short* __restrict__ X,
                                                 const short* __restrict__ Wt,
                                                 const short* __restrict__ bias,
                                                 void* __restrict__ outv,
                                                 const int* __restrict__ flag)
{
    const int lane = threadIdx.x & 63;
    const int wave = threadIdx.x >> 6;
    const int quad = lane >> 4;
    const int l16  = lane & 15;
    const int m0 = blockIdx.x * 128 + wave * 32;
    const int n0 = blockIdx.y * 64;

    f32x4 acc[2][4];
#pragma unroll
    for (int t = 0; t < 4; ++t) {
        const float bv = bf2f(bias[n0 + t*16 + l16]);
#pragma unroll
        for (int mg = 0; mg < 2; ++mg) acc[mg][t] = (f32x4){bv, bv, bv, bv};
    }

    for (int k0 = 0; k0 < D_MODEL; k0 += 32) {
        short8 a[2];
#pragma unroll
        for (int mg = 0; mg < 2; ++mg)
            a[mg] = *(const short8*)(X + (size_t)(m0 + mg*16 + l16) * D_MODEL + k0 + quad*8);
#pragma unroll
        for (int t = 0; t < 4; ++t) {
            short8 bfr = *(const short8*)(Wt + (size_t)(n0 + t*16 + l16) * D_MODEL + k0 + quad*8);
#pragma unroll
            for (int mg = 0; mg < 2; ++mg)
                acc[mg][t] = __builtin_amdgcn_mfma_f32_16x16x32_bf16(a[mg], bfr, acc[mg][t], 0, 0, 0);
        }
    }

    const bool outf32 = (OMODE == 1) && (*flag != 0);
#pragma unroll
    for (int mg = 0; mg < 2; ++mg)
#pragma unroll
    for (int t = 0; t < 4; ++t) {
        const int n = n0 + t*16 + l16;
#pragma unroll
        for (int r = 0; r < 4; ++r) {
            const int m = m0 + mg*16 + quad*4 + r;
            const size_t idx = (size_t)m * D_MODEL + n;
            if (outf32) ((float*)outv)[idx] = acc[mg][t][r];
            else        ((short*)outv)[idx] = f2bf(acc[mg][t][r]);
        }
    }
}

// ---------------------------------------------------------------------------
// MFMA flash attention. Block = 256 thr = 4 waves; 128 queries/block for one
// (b,h); 32 K-tiles of 64 keys. S^T = K*Q^T (bf16 MFMA), online softmax,
// O^T = V^T * P^T (f16 MFMA). All LDS rows padded to stride 72 (16B-aligned,
// breaks 128B bank periodicity). P round-trips through per-wave LDS.
// ---------------------------------------------------------------------------
#define LSTR 72
__global__ __launch_bounds__(256) void attn_mfma(const short* __restrict__ q,
                                                 const short* __restrict__ k,
                                                 const short* __restrict__ v,
                                                 short* __restrict__ ctx)
{
    __shared__ short   Kls[64 * LSTR];            // [key][dim]   9216 B
    __shared__ _Float16 VT[64 * LSTR];            // [dim][key]   9216 B
    __shared__ _Float16 Pls[4][32 * LSTR];        // per-wave [q][key] 18432 B

    const int tid  = threadIdx.x;
    const int wave = tid >> 6, lane = tid & 63;
    const int quad = lane >> 4, l16 = lane & 15;
    const int b = blockIdx.y / NHEADS, h = blockIdx.y % NHEADS;
    const int q0 = blockIdx.x * 128;

    // Q^T B-frags held in registers for the whole K loop: [qg][k0h]
    short8 qf[2][2];
#pragma unroll
    for (int qg = 0; qg < 2; ++qg)
#pragma unroll
    for (int k0h = 0; k0h < 2; ++k0h)
        qf[qg][k0h] = *(const short8*)(q + (size_t)(b*SEQ + q0 + wave*32 + qg*16 + l16) * D_MODEL
                                         + h*HD + k0h*32 + quad*8);

    float m_[2] = { -1e30f, -1e30f }, l_[2] = { 0.f, 0.f };
    f32x4 o[2][4];
#pragma unroll
    for (int qg = 0; qg < 2; ++qg)
#pragma unroll
    for (int t = 0; t < 4; ++t) o[qg][t] = (f32x4){0.f, 0.f, 0.f, 0.f};

    for (int jt = 0; jt < SEQ / 64; ++jt) {
        const int j0 = jt * 64;
        __syncthreads();   // previous tile's reads done before restage
        // ---- stage K tile [key][dim], coalesced, b128 writes ----
#pragma unroll
        for (int u = 0; u < 2; ++u) {
            const int e = tid + u * 256;
            const int key = e >> 3, c8 = e & 7;
            short8 kv = *(const short8*)(k + (size_t)(b*SEQ + j0 + key) * D_MODEL + h*HD + c8*8);
            *(short8*)&Kls[key * LSTR + c8 * 8] = kv;
        }
        // ---- stage V^T tile [dim][key] as f16 (exact from bf16) ----
#pragma unroll
        for (int u = 0; u < 2; ++u) {
            const int key = tid & 63, dc = (tid >> 6) + u * 4;
            short8 vv = *(const short8*)(v + (size_t)(b*SEQ + j0 + key) * D_MODEL + h*HD + dc*8);
#pragma unroll
            for (int i = 0; i < 8; ++i)
                VT[(dc*8 + i) * LSTR + key] = (_Float16)bf2f(vv[i]);
        }
        __syncthreads();

        // ---- S^T = K * Q^T : D[m=key][n=query] ----
        f32x4 s[2][4];
#pragma unroll
        for (int qg = 0; qg < 2; ++qg)
#pragma unroll
        for (int t = 0; t < 4; ++t) s[qg][t] = (f32x4){0.f, 0.f, 0.f, 0.f};
#pragma unroll
        for (int k0h = 0; k0h < 2; ++k0h)
#pragma unroll
        for (int t = 0; t < 4; ++t) {
            short8 kf = *(const short8*)&Kls[(t*16 + l16) * LSTR + k0h*32 + quad*8];
#pragma unroll
            for (int qg = 0; qg < 2; ++qg)
                s[qg][t] = __builtin_amdgcn_mfma_f32_16x16x32_bf16(kf, qf[qg][k0h], s[qg][t], 0, 0, 0);
        }

        // ---- online softmax per query (col = l16); keys spread over quads ----
#pragma unroll
        for (int qg = 0; qg < 2; ++qg) {
            float p[4][4];
            float mx = -1e30f;
#pragma unroll
            for (int t = 0; t < 4; ++t)
#pragma unroll
            for (int r = 0; r < 4; ++r) {
                p[t][r] = s[qg][t][r] * 0.125f;
                mx = fmaxf(mx, p[t][r]);
            }
            mx = fmaxf(mx, __shfl_xor(mx, 16));
            mx = fmaxf(mx, __shfl_xor(mx, 32));
            const float mn = fmaxf(m_[qg], mx);
            const float al = __expf(m_[qg] - mn);
            float rs = 0.f;
#pragma unroll
            for (int t = 0; t < 4; ++t)
#pragma unroll
            for (int r = 0; r < 4; ++r) {
                p[t][r] = __expf(p[t][r] - mn);
                rs += p[t][r];
            }
            rs += __shfl_xor(rs, 16);
            rs += __shfl_xor(rs, 32);
            l_[qg] = l_[qg] * al + rs;
            m_[qg] = mn;
#pragma unroll
            for (int t = 0; t < 4; ++t) {
                o[qg][t][0] *= al; o[qg][t][1] *= al; o[qg][t][2] *= al; o[qg][t][3] *= al;
                union { _Float16 h[4]; int2 v; } u4;
#pragma unroll
                for (int r = 0; r < 4; ++r) u4.h[r] = (_Float16)p[t][r];
                *(int2*)&Pls[wave][(qg*16 + l16) * LSTR + t*16 + quad*4] = u4.v;
            }
        }
        // Pls is per-wave: same-wave ds write->read needs only lgkmcnt (compiler).

        // ---- O^T += V^T * P^T : D[m=dim][n=query] ----
#pragma unroll
        for (int k0h = 0; k0h < 2; ++k0h) {
            half8 pf[2];
#pragma unroll
            for (int qg = 0; qg < 2; ++qg)
                pf[qg] = *(half8*)&Pls[wave][(qg*16 + l16) * LSTR + k0h*32 + quad*8];
#pragma unroll
            for (int t = 0; t < 4; ++t) {
                half8 vf = *(half8*)&VT[(t*16 + l16) * LSTR + k0h*32 + quad*8];
#pragma unroll
                for (int qg = 0; qg < 2; ++qg)
                    o[qg][t] = __builtin_amdgcn_mfma_f32_16x16x32_f16(vf, pf[qg], o[qg][t], 0, 0, 0);
            }
        }
    }

    // ---- normalize + write ctx (pack 4 consecutive dims -> 8B store) ----
#pragma unroll
    for (int qg = 0; qg < 2; ++qg) {
        const float inv = 1.0f / l_[qg];
        const size_t row = (size_t)(b*SEQ + q0 + wave*32 + qg*16 + l16) * D_MODEL + h*HD;
#pragma unroll
        for (int t = 0; t < 4; ++t) {
            union { short s[4]; int2 v; } u4;
#pragma unroll
            for (int r = 0; r < 4; ++r) u4.s[r] = f2bf(o[qg][t][r] * inv);
            *(int2*)(ctx + row + t*16 + quad*4) = u4.v;
        }
    }
}

// ---------------------------------------------------------------------------
extern "C" void kernel_launch(void* const* d_in, const int* in_sizes, int n_in,
                              void* d_out, int out_size, void* d_ws, size_t ws_size,
                              hipStream_t stream)
{
    int* flag = (int*)d_ws;
    short* xc = (short*)((char*)d_ws + 64);
    short* Wt = xc + NX;           // 4 transposed weights: q,k,v,o
    short* bc = Wt + 4 * NW;       // 4 biases
    short* qb = bc + 4 * D_MODEL;
    short* kb = qb + NX;
    short* vb = kb + NX;
    short* cb = vb + NX;

    detect_dtype<<<1, 256, 0, stream>>>((const short*)d_in[0], flag);

    conv_x4<<<(int)(NX/4 + 255) / 256, 256, 0, stream>>>(d_in[0], xc, (int)(NX/4), flag);
    conv_wt<<<dim3(12, 12, 4), 256, 0, stream>>>(d_in[1], d_in[3], d_in[5], d_in[7], Wt, flag);
    conv_bias<<<1, 256, 0, stream>>>(d_in[2], d_in[4], d_in[6], d_in[8], bc, flag);

    dim3 blk(256);
    // fused QKV: blockIdx.z selects weight/bias/output
    {
        // launch 3 separate to keep template simple but same kernel
        proj_gemm<0><<<dim3(NTOK/128, D_MODEL/64), blk, 0, stream>>>(xc, Wt + 0*NW, bc + 0*D_MODEL, qb, flag);
        proj_gemm<0><<<dim3(NTOK/128, D_MODEL/64), blk, 0, stream>>>(xc, Wt + 1*NW, bc + 1*D_MODEL, kb, flag);
        proj_gemm<0><<<dim3(NTOK/128, D_MODEL/64), blk, 0, stream>>>(xc, Wt + 2*NW, bc + 2*D_MODEL, vb, flag);
    }

    attn_mfma<<<dim3(SEQ/128, BATCH*NHEADS), blk, 0, stream>>>(qb, kb, vb, cb);

    proj_gemm<1><<<dim3(NTOK/128, D_MODEL/64), blk, 0, stream>>>(cb, Wt + 3*NW, bc + 3*D_MODEL, d_out, flag);
}

// Round 4
// 244.172 us; speedup vs baseline: 13.6420x; 1.3436x over previous
//
#include <hip/hip_runtime.h>
#include <hip/hip_bf16.h>
#include <hip/hip_fp16.h>

#define D_MODEL 768
#define NHEADS  12
#define HD      64
#define BATCH   2
#define SEQ     2048
#define NTOK    (BATCH*SEQ)   // 4096
#define NX      ((size_t)NTOK * D_MODEL)     // 3,145,728
#define NW      ((size_t)D_MODEL * D_MODEL)  // 589,824

typedef __attribute__((ext_vector_type(8))) short    short8;
typedef __attribute__((ext_vector_type(8))) _Float16 half8;
typedef __attribute__((ext_vector_type(4))) float    f32x4;

__device__ __forceinline__ float bf2f(short s) {
    union { unsigned u; float f; } c;
    c.u = ((unsigned)(unsigned short)s) << 16;
    return c.f;
}
__device__ __forceinline__ short f2bf(float f) {
    __hip_bfloat16 h = __float2bfloat16(f);
    return *(short*)&h;
}

#ifdef __has_builtin
#if __has_builtin(__builtin_amdgcn_global_load_lds)
#define HAS_GLD 1
#endif
#endif
#ifdef HAS_GLD
#define GLD16(gp, lp) __builtin_amdgcn_global_load_lds( \
    (const __attribute__((address_space(1))) void*)(gp), \
    (__attribute__((address_space(3))) void*)(lp), 16, 0, 0)
#endif

// ---------------------------------------------------------------------------
// Dtype detector: 1 = inputs fp32, 0 = inputs bf16.
// ---------------------------------------------------------------------------
__global__ void detect_dtype(const short* __restrict__ x, int* __restrict__ flag) {
    __shared__ int red[256];
    const int tid = threadIdx.x;
    int maxe = 0;
    for (int i = tid; i < 4096; i += 256) {
        int e = ((unsigned short)x[i] >> 7) & 0xFF;
        maxe = max(maxe, e);
    }
    red[tid] = maxe;
    __syncthreads();
    for (int s = 128; s > 0; s >>= 1) {
        if (tid < s) red[tid] = max(red[tid], red[tid + s]);
        __syncthreads();
    }
    if (tid == 0) *flag = (red[0] > 140) ? 1 : 0;
}

__global__ void conv_x4(const void* __restrict__ src, short* __restrict__ dst,
                        int n4, const int* __restrict__ flag) {
    const int i = blockIdx.x * 256 + threadIdx.x;
    if (i >= n4) return;
    if (*flag) {
        float4 f = ((const float4*)src)[i];
        short4 o = { f2bf(f.x), f2bf(f.y), f2bf(f.z), f2bf(f.w) };
        ((short4*)dst)[i] = o;
    } else {
        ((short4*)dst)[i] = ((const short4*)src)[i];
    }
}

// Fused convert+transpose of the 4 weight matrices: Wt[n][k] = W[k][n], bf16.
__global__ __launch_bounds__(256) void conv_wt(const void* __restrict__ w0,
                                               const void* __restrict__ w1,
                                               const void* __restrict__ w2,
                                               const void* __restrict__ w3,
                                               short* __restrict__ wt,
                                               const int* __restrict__ flag)
{
    __shared__ float T[64][65];
    const int z = blockIdx.z;
    const void* src = (z == 0) ? w0 : (z == 1) ? w1 : (z == 2) ? w2 : w3;
    const int k0 = blockIdx.x * 64, n0 = blockIdx.y * 64;
    const int a = threadIdx.x & 15, b = threadIdx.x >> 4;
    const bool isf = (*flag != 0);
#pragma unroll
    for (int u = 0; u < 4; ++u) {
        const int kr = (b & 3) + 4 * u + 16 * (b >> 2);
        if (isf) {
            float4 f = *(const float4*)((const float*)src + (size_t)(k0 + kr) * D_MODEL + n0 + a * 4);
            T[kr][a*4+0] = f.x; T[kr][a*4+1] = f.y; T[kr][a*4+2] = f.z; T[kr][a*4+3] = f.w;
        } else {
            short4 s = *(const short4*)((const short*)src + (size_t)(k0 + kr) * D_MODEL + n0 + a * 4);
            T[kr][a*4+0] = bf2f(s.x); T[kr][a*4+1] = bf2f(s.y); T[kr][a*4+2] = bf2f(s.z); T[kr][a*4+3] = bf2f(s.w);
        }
    }
    __syncthreads();
#pragma unroll
    for (int u = 0; u < 4; ++u) {
        const int nr = (b & 3) + 4 * u + 16 * (b >> 2);
        short4 o = { f2bf(T[a*4+0][nr]), f2bf(T[a*4+1][nr]),
                     f2bf(T[a*4+2][nr]), f2bf(T[a*4+3][nr]) };
        *(short4*)(wt + (size_t)z * NW + (size_t)(n0 + nr) * D_MODEL + k0 + a * 4) = o;
    }
}

__global__ void conv_bias(const void* __restrict__ b0, const void* __restrict__ b1,
                          const void* __restrict__ b2, const void* __restrict__ b3,
                          short* __restrict__ dst, const int* __restrict__ flag)
{
    const int tid = threadIdx.x;
    const void* srcs[4] = { b0, b1, b2, b3 };
    const bool isf = (*flag != 0);
    for (int z = 0; z < 4; ++z)
        for (int i = tid; i < D_MODEL; i += 256) {
            short o = isf ? f2bf(((const float*)srcs[z])[i]) : ((const short*)srcs[z])[i];
            dst[z * D_MODEL + i] = o;
        }
}

// ---------------------------------------------------------------------------
// Fused QKV GEMM (m97 structure): OUT[4096][2304] = X @ [Wq|Wk|Wv] + bias.
// Block 256 thr = 2x2 waves; tile 128x128, BK=32, LDS staging via
// global_load_lds width=16. Epilogue: y<6 -> qb rows, y<12 -> kb rows,
// y>=12 -> Vt f16 [bh][dim][SEQ] transposed with packed 8B stores.
// ---------------------------------------------------------------------------
__global__ __launch_bounds__(256) void qkv_gemm(const short* __restrict__ X,
                                                const short* __restrict__ Wt,
                                                const short* __restrict__ bias,
                                                short* __restrict__ qb,
                                                short* __restrict__ kb,
                                                _Float16* __restrict__ Vt)
{
    __shared__ short Als[128 * 32];
    __shared__ short Bls[128 * 32];

    const int tid = threadIdx.x;
    const int wave = tid >> 6, lane = tid & 63;
    const int quad = lane >> 4, l16 = lane & 15;
    const int wm = wave & 1, wn = wave >> 1;
    const int m0 = blockIdx.x * 128;
    const int ng = blockIdx.y * 128;

    f32x4 acc[4][4];
#pragma unroll
    for (int nt = 0; nt < 4; ++nt) {
        const float bv = bf2f(bias[ng + wn*64 + nt*16 + l16]);
#pragma unroll
        for (int mt = 0; mt < 4; ++mt) acc[mt][nt] = (f32x4){bv, bv, bv, bv};
    }

    const int row = tid >> 2, ch = (tid & 3) * 8;
    for (int k0 = 0; k0 < D_MODEL; k0 += 32) {
        __syncthreads();
        const short* ga0 = X  + (size_t)(m0 + row)      * D_MODEL + k0 + ch;
        const short* ga1 = X  + (size_t)(m0 + 64 + row) * D_MODEL + k0 + ch;
        const short* gb0 = Wt + (size_t)(ng + row)      * D_MODEL + k0 + ch;
        const short* gb1 = Wt + (size_t)(ng + 64 + row) * D_MODEL + k0 + ch;
#ifdef HAS_GLD
        GLD16(ga0, &Als[tid * 8]);
        GLD16(ga1, &Als[2048 + tid * 8]);
        GLD16(gb0, &Bls[tid * 8]);
        GLD16(gb1, &Bls[2048 + tid * 8]);
#else
        short8 r0 = *(const short8*)ga0, r1 = *(const short8*)ga1;
        short8 r2 = *(const short8*)gb0, r3 = *(const short8*)gb1;
        *(short8*)&Als[tid * 8] = r0;  *(short8*)&Als[2048 + tid * 8] = r1;
        *(short8*)&Bls[tid * 8] = r2;  *(short8*)&Bls[2048 + tid * 8] = r3;
#endif
        __syncthreads();

        short8 a[4], b[4];
#pragma unroll
        for (int mt = 0; mt < 4; ++mt)
            a[mt] = *(const short8*)&Als[(wm*64 + mt*16 + l16) * 32 + quad*8];
#pragma unroll
        for (int nt = 0; nt < 4; ++nt)
            b[nt] = *(const short8*)&Bls[(wn*64 + nt*16 + l16) * 32 + quad*8];
#pragma unroll
        for (int mt = 0; mt < 4; ++mt)
#pragma unroll
        for (int nt = 0; nt < 4; ++nt)
            acc[mt][nt] = __builtin_amdgcn_mfma_f32_16x16x32_bf16(a[mt], b[nt], acc[mt][nt], 0, 0, 0);
    }

    const int seg = blockIdx.y / 6;   // 0=q, 1=k, 2=v
    if (seg < 2) {
        short* out = seg ? kb : qb;
        const int nl = ng - seg * 768;
#pragma unroll
        for (int mt = 0; mt < 4; ++mt)
#pragma unroll
        for (int nt = 0; nt < 4; ++nt) {
            const int n = nl + wn*64 + nt*16 + l16;
#pragma unroll
            for (int r = 0; r < 4; ++r) {
                const int m = m0 + wm*64 + mt*16 + quad*4 + r;
                out[(size_t)m * D_MODEL + n] = f2bf(acc[mt][nt][r]);
            }
        }
    } else {
#pragma unroll
        for (int nt = 0; nt < 4; ++nt) {
            const int nv = ng - 1536 + wn*64 + nt*16 + l16;
            const int h = nv >> 6, d = nv & 63;
#pragma unroll
            for (int mt = 0; mt < 4; ++mt) {
                const int m = m0 + wm*64 + mt*16 + quad*4;
                union { _Float16 h4[4]; int2 v; } u;
#pragma unroll
                for (int r = 0; r < 4; ++r) u.h4[r] = (_Float16)acc[mt][nt][r];
                *(int2*)&Vt[((size_t)((m >> 11) * NHEADS + h) * HD + d) * SEQ + (m & (SEQ-1))] = u.v;
            }
        }
    }
}

// ---------------------------------------------------------------------------
// Output projection (same structure, N=768): out = ctx @ Wo + bo.
// ---------------------------------------------------------------------------
__global__ __launch_bounds__(256) void out_gemm(const short* __restrict__ X,
                                                const short* __restrict__ Wt,
                                                const short* __restrict__ bias,
                                                void* __restrict__ outv,
                                                const int* __restrict__ flag)
{
    __shared__ short Als[128 * 32];
    __shared__ short Bls[128 * 32];

    const int tid = threadIdx.x;
    const int wave = tid >> 6, lane = tid & 63;
    const int quad = lane >> 4, l16 = lane & 15;
    const int wm = wave & 1, wn = wave >> 1;
    const int m0 = blockIdx.x * 128;
    const int ng = blockIdx.y * 128;

    f32x4 acc[4][4];
#pragma unroll
    for (int nt = 0; nt < 4; ++nt) {
        const float bv = bf2f(bias[ng + wn*64 + nt*16 + l16]);
#pragma unroll
        for (int mt = 0; mt < 4; ++mt) acc[mt][nt] = (f32x4){bv, bv, bv, bv};
    }

    const int row = tid >> 2, ch = (tid & 3) * 8;
    for (int k0 = 0; k0 < D_MODEL; k0 += 32) {
        __syncthreads();
        const short* ga0 = X  + (size_t)(m0 + row)      * D_MODEL + k0 + ch;
        const short* ga1 = X  + (size_t)(m0 + 64 + row) * D_MODEL + k0 + ch;
        const short* gb0 = Wt + (size_t)(ng + row)      * D_MODEL + k0 + ch;
        const short* gb1 = Wt + (size_t)(ng + 64 + row) * D_MODEL + k0 + ch;
#ifdef HAS_GLD
        GLD16(ga0, &Als[tid * 8]);
        GLD16(ga1, &Als[2048 + tid * 8]);
        GLD16(gb0, &Bls[tid * 8]);
        GLD16(gb1, &Bls[2048 + tid * 8]);
#else
        short8 r0 = *(const short8*)ga0, r1 = *(const short8*)ga1;
        short8 r2 = *(const short8*)gb0, r3 = *(const short8*)gb1;
        *(short8*)&Als[tid * 8] = r0;  *(short8*)&Als[2048 + tid * 8] = r1;
        *(short8*)&Bls[tid * 8] = r2;  *(short8*)&Bls[2048 + tid * 8] = r3;
#endif
        __syncthreads();

        short8 a[4], b[4];
#pragma unroll
        for (int mt = 0; mt < 4; ++mt)
            a[mt] = *(const short8*)&Als[(wm*64 + mt*16 + l16) * 32 + quad*8];
#pragma unroll
        for (int nt = 0; nt < 4; ++nt)
            b[nt] = *(const short8*)&Bls[(wn*64 + nt*16 + l16) * 32 + quad*8];
#pragma unroll
        for (int mt = 0; mt < 4; ++mt)
#pragma unroll
        for (int nt = 0; nt < 4; ++nt)
            acc[mt][nt] = __builtin_amdgcn_mfma_f32_16x16x32_bf16(a[mt], b[nt], acc[mt][nt], 0, 0, 0);
    }

    const bool outf32 = (*flag != 0);
#pragma unroll
    for (int mt = 0; mt < 4; ++mt)
#pragma unroll
    for (int nt = 0; nt < 4; ++nt) {
        const int n = ng + wn*64 + nt*16 + l16;
#pragma unroll
        for (int r = 0; r < 4; ++r) {
            const int m = m0 + wm*64 + mt*16 + quad*4 + r;
            const size_t idx = (size_t)m * D_MODEL + n;
            if (outf32) ((float*)outv)[idx] = acc[mt][nt][r];
            else        ((short*)outv)[idx] = f2bf(acc[mt][nt][r]);
        }
    }
}

// ---------------------------------------------------------------------------
// Barrier-free MFMA flash attention. Block = 128 thr = 2 waves; 64 q/block.
// K-frags and Vt-frags direct from global (all waves read identical addrs ->
// L1/L2 dedup). LDS: per-wave P round-trip only. No __syncthreads at all.
// ---------------------------------------------------------------------------
#define LSTR 72
__global__ __launch_bounds__(128) void attn_mfma(const short* __restrict__ q,
                                                 const short* __restrict__ k,
                                                 const _Float16* __restrict__ Vt,
                                                 short* __restrict__ ctx)
{
    __shared__ _Float16 Pls[2][32 * LSTR];   // 9216 B

    const int tid  = threadIdx.x;
    const int wave = tid >> 6, lane = tid & 63;
    const int quad = lane >> 4, l16 = lane & 15;
    const int bh = blockIdx.y;
    const int b = bh / NHEADS, h = bh % NHEADS;
    const size_t bS = (size_t)b * SEQ;
    const int qrow0 = blockIdx.x * 64 + wave * 32;

    short8 qf[2][2];
#pragma unroll
    for (int qg = 0; qg < 2; ++qg)
#pragma unroll
    for (int k0h = 0; k0h < 2; ++k0h)
        qf[qg][k0h] = *(const short8*)(q + (bS + qrow0 + qg*16 + l16) * D_MODEL
                                         + h*HD + k0h*32 + quad*8);

    float m_[2] = { -1e30f, -1e30f }, l_[2] = { 0.f, 0.f };
    f32x4 o[2][4];
#pragma unroll
    for (int qg = 0; qg < 2; ++qg)
#pragma unroll
    for (int t = 0; t < 4; ++t) o[qg][t] = (f32x4){0.f, 0.f, 0.f, 0.f};

    for (int jt = 0; jt < SEQ / 64; ++jt) {
        const int j0 = jt * 64;

        // ---- K frags (global, b128) ----
        short8 kf[4][2];
#pragma unroll
        for (int t = 0; t < 4; ++t)
#pragma unroll
        for (int k0h = 0; k0h < 2; ++k0h)
            kf[t][k0h] = *(const short8*)(k + (bS + j0 + t*16 + l16) * D_MODEL
                                            + h*HD + k0h*32 + quad*8);
        // ---- Vt frags issued now; latency hides behind softmax ----
        half8 vf[4][2];
#pragma unroll
        for (int t = 0; t < 4; ++t)
#pragma unroll
        for (int k0h = 0; k0h < 2; ++k0h)
            vf[t][k0h] = *(const half8*)(Vt + ((size_t)bh * HD + t*16 + l16) * SEQ
                                            + j0 + k0h*32 + quad*8);

        // ---- S^T = K * Q^T ----
        f32x4 s[2][4];
#pragma unroll
        for (int qg = 0; qg < 2; ++qg)
#pragma unroll
        for (int t = 0; t < 4; ++t) s[qg][t] = (f32x4){0.f, 0.f, 0.f, 0.f};
#pragma unroll
        for (int k0h = 0; k0h < 2; ++k0h)
#pragma unroll
        for (int t = 0; t < 4; ++t)
#pragma unroll
        for (int qg = 0; qg < 2; ++qg)
            s[qg][t] = __builtin_amdgcn_mfma_f32_16x16x32_bf16(kf[t][k0h], qf[qg][k0h], s[qg][t], 0, 0, 0);

        // ---- online softmax (query = l16 col) ----
#pragma unroll
        for (int qg = 0; qg < 2; ++qg) {
            float p[4][4];
            float mx = -1e30f;
#pragma unroll
            for (int t = 0; t < 4; ++t)
#pragma unroll
            for (int r = 0; r < 4; ++r) {
                p[t][r] = s[qg][t][r] * 0.125f;
                mx = fmaxf(mx, p[t][r]);
            }
            mx = fmaxf(mx, __shfl_xor(mx, 16));
            mx = fmaxf(mx, __shfl_xor(mx, 32));
            const float mn = fmaxf(m_[qg], mx);
            const float al = __expf(m_[qg] - mn);
            float rs = 0.f;
#pragma unroll
            for (int t = 0; t < 4; ++t)
#pragma unroll
            for (int r = 0; r < 4; ++r) {
                p[t][r] = __expf(p[t][r] - mn);
                rs += p[t][r];
            }
            rs += __shfl_xor(rs, 16);
            rs += __shfl_xor(rs, 32);
            l_[qg] = l_[qg] * al + rs;
            m_[qg] = mn;
#pragma unroll
            for (int t = 0; t < 4; ++t) {
                o[qg][t][0] *= al; o[qg][t][1] *= al; o[qg][t][2] *= al; o[qg][t][3] *= al;
                union { _Float16 h4[4]; int2 v; } u4;
#pragma unroll
                for (int r = 0; r < 4; ++r) u4.h4[r] = (_Float16)p[t][r];
                *(int2*)&Pls[wave][(qg*16 + l16) * LSTR + t*16 + quad*4] = u4.v;
            }
        }

        // ---- O^T += V^T * P^T ----
#pragma unroll
        for (int k0h = 0; k0h < 2; ++k0h) {
            half8 pf[2];
#pragma unroll
            for (int qg = 0; qg < 2; ++qg)
                pf[qg] = *(half8*)&Pls[wave][(qg*16 + l16) * LSTR + k0h*32 + quad*8];
#pragma unroll
            for (int t = 0; t < 4; ++t)
#pragma unroll
            for (int qg = 0; qg < 2; ++qg)
                o[qg][t] = __builtin_amdgcn_mfma_f32_16x16x32_f16(vf[t][k0h], pf[qg], o[qg][t], 0, 0, 0);
        }
    }

    // ---- normalize + packed bf16 stores ----
#pragma unroll
    for (int qg = 0; qg < 2; ++qg) {
        const float inv = 1.0f / l_[qg];
        const size_t rowp = (bS + qrow0 + qg*16 + l16) * D_MODEL + h*HD;
#pragma unroll
        for (int t = 0; t < 4; ++t) {
            union { short s4[4]; int2 v; } u4;
#pragma unroll
            for (int r = 0; r < 4; ++r) u4.s4[r] = f2bf(o[qg][t][r] * inv);
            *(int2*)(ctx + rowp + t*16 + quad*4) = u4.v;
        }
    }
}

// ---------------------------------------------------------------------------
extern "C" void kernel_launch(void* const* d_in, const int* in_sizes, int n_in,
                              void* d_out, int out_size, void* d_ws, size_t ws_size,
                              hipStream_t stream)
{
    int* flag = (int*)d_ws;
    short* xc = (short*)((char*)d_ws + 64);
    short* Wt = xc + NX;                 // [2304+768][768] transposed, q|k|v|o
    short* bc = Wt + 4 * NW;             // biases q|k|v|o
    short* qb = bc + 4 * D_MODEL;
    short* kb = qb + NX;
    _Float16* Vt = (_Float16*)(kb + NX); // [24][64][2048] f16
    short* cb = (short*)(Vt + NX);

    detect_dtype<<<1, 256, 0, stream>>>((const short*)d_in[0], flag);
    conv_x4<<<(int)(NX/4 + 255) / 256, 256, 0, stream>>>(d_in[0], xc, (int)(NX/4), flag);
    conv_wt<<<dim3(12, 12, 4), 256, 0, stream>>>(d_in[1], d_in[3], d_in[5], d_in[7], Wt, flag);
    conv_bias<<<1, 256, 0, stream>>>(d_in[2], d_in[4], d_in[6], d_in[8], bc, flag);

    qkv_gemm<<<dim3(NTOK/128, 2304/128), 256, 0, stream>>>(xc, Wt, bc, qb, kb, Vt);

    attn_mfma<<<dim3(SEQ/64, BATCH*NHEADS), 128, 0, stream>>>(qb, kb, Vt, cb);

    out_gemm<<<dim3(NTOK/128, D_MODEL/128), 256, 0, stream>>>(cb, Wt + 3*NW, bc + 3*D_MODEL, d_out, flag);
}

// Round 5
// 238.486 us; speedup vs baseline: 13.9672x; 1.0238x over previous
//
#include <hip/hip_runtime.h>
#include <hip/hip_bf16.h>
#include <hip/hip_fp16.h>

#define D_MODEL 768
#define NHEADS  12
#define HD      64
#define BATCH   2
#define SEQ     2048
#define NTOK    (BATCH*SEQ)   // 4096
#define NX      ((size_t)NTOK * D_MODEL)     // 3,145,728
#define NW      ((size_t)D_MODEL * D_MODEL)  // 589,824

typedef __attribute__((ext_vector_type(8))) short    short8;
typedef __attribute__((ext_vector_type(8))) _Float16 half8;
typedef __attribute__((ext_vector_type(4))) float    f32x4;

__device__ __forceinline__ float bf2f(short s) {
    union { unsigned u; float f; } c;
    c.u = ((unsigned)(unsigned short)s) << 16;
    return c.f;
}
__device__ __forceinline__ short f2bf(float f) {
    __hip_bfloat16 h = __float2bfloat16(f);
    return *(short*)&h;
}

#ifdef __has_builtin
#if __has_builtin(__builtin_amdgcn_global_load_lds)
#define HAS_GLD 1
#endif
#endif
#ifdef HAS_GLD
#define GLD16(gp, lp) __builtin_amdgcn_global_load_lds( \
    (const __attribute__((address_space(1))) void*)(gp), \
    (__attribute__((address_space(3))) void*)(lp), 16, 0, 0)
#endif

// ---------------------------------------------------------------------------
// Dtype detect (1 = fp32 inputs) + bias conversion, one launch.
// ---------------------------------------------------------------------------
__global__ void detect_and_bias(const short* __restrict__ x, int* __restrict__ flag,
                                const void* __restrict__ b0, const void* __restrict__ b1,
                                const void* __restrict__ b2, const void* __restrict__ b3,
                                short* __restrict__ dst)
{
    __shared__ int red[256];
    const int tid = threadIdx.x;
    int maxe = 0;
    for (int i = tid; i < 4096; i += 256) {
        int e = ((unsigned short)x[i] >> 7) & 0xFF;
        maxe = max(maxe, e);
    }
    red[tid] = maxe;
    __syncthreads();
    for (int s = 128; s > 0; s >>= 1) {
        if (tid < s) red[tid] = max(red[tid], red[tid + s]);
        __syncthreads();
    }
    const bool isf = (red[0] > 140);
    if (tid == 0) *flag = isf ? 1 : 0;
    const void* srcs[4] = { b0, b1, b2, b3 };
    for (int z = 0; z < 4; ++z)
        for (int i = tid; i < D_MODEL; i += 256) {
            short o = isf ? f2bf(((const float*)srcs[z])[i]) : ((const short*)srcs[z])[i];
            dst[z * D_MODEL + i] = o;
        }
}

__global__ void conv_x4(const void* __restrict__ src, short* __restrict__ dst,
                        int n4, const int* __restrict__ flag) {
    const int i = blockIdx.x * 256 + threadIdx.x;
    if (i >= n4) return;
    if (*flag) {
        float4 f = ((const float4*)src)[i];
        short4 o = { f2bf(f.x), f2bf(f.y), f2bf(f.z), f2bf(f.w) };
        ((short4*)dst)[i] = o;
    } else {
        ((short4*)dst)[i] = ((const short4*)src)[i];
    }
}

// Fused convert+transpose of the 4 weight matrices: Wt[n][k] = W[k][n], bf16.
__global__ __launch_bounds__(256) void conv_wt(const void* __restrict__ w0,
                                               const void* __restrict__ w1,
                                               const void* __restrict__ w2,
                                               const void* __restrict__ w3,
                                               short* __restrict__ wt,
                                               const int* __restrict__ flag)
{
    __shared__ float T[64][65];
    const int z = blockIdx.z;
    const void* src = (z == 0) ? w0 : (z == 1) ? w1 : (z == 2) ? w2 : w3;
    const int k0 = blockIdx.x * 64, n0 = blockIdx.y * 64;
    const int a = threadIdx.x & 15, b = threadIdx.x >> 4;
    const bool isf = (*flag != 0);
#pragma unroll
    for (int u = 0; u < 4; ++u) {
        const int kr = (b & 3) + 4 * u + 16 * (b >> 2);
        if (isf) {
            float4 f = *(const float4*)((const float*)src + (size_t)(k0 + kr) * D_MODEL + n0 + a * 4);
            T[kr][a*4+0] = f.x; T[kr][a*4+1] = f.y; T[kr][a*4+2] = f.z; T[kr][a*4+3] = f.w;
        } else {
            short4 s = *(const short4*)((const short*)src + (size_t)(k0 + kr) * D_MODEL + n0 + a * 4);
            T[kr][a*4+0] = bf2f(s.x); T[kr][a*4+1] = bf2f(s.y); T[kr][a*4+2] = bf2f(s.z); T[kr][a*4+3] = bf2f(s.w);
        }
    }
    __syncthreads();
#pragma unroll
    for (int u = 0; u < 4; ++u) {
        const int nr = (b & 3) + 4 * u + 16 * (b >> 2);
        short4 o = { f2bf(T[a*4+0][nr]), f2bf(T[a*4+1][nr]),
                     f2bf(T[a*4+2][nr]), f2bf(T[a*4+3][nr]) };
        *(short4*)(wt + (size_t)z * NW + (size_t)(n0 + nr) * D_MODEL + k0 + a * 4) = o;
    }
}

// ---------------------------------------------------------------------------
// Fused QKV GEMM: OUT[4096][2304] = X @ [Wq|Wk|Wv] + bias. 128x128 tile,
// BK=32, global_load_lds staging. V segment -> Vt f16 [bh][dim][SEQ].
// ---------------------------------------------------------------------------
__global__ __launch_bounds__(256) void qkv_gemm(const short* __restrict__ X,
                                                const short* __restrict__ Wt,
                                                const short* __restrict__ bias,
                                                short* __restrict__ qb,
                                                short* __restrict__ kb,
                                                _Float16* __restrict__ Vt)
{
    __shared__ short Als[128 * 32];
    __shared__ short Bls[128 * 32];

    const int tid = threadIdx.x;
    const int wave = tid >> 6, lane = tid & 63;
    const int quad = lane >> 4, l16 = lane & 15;
    const int wm = wave & 1, wn = wave >> 1;
    const int m0 = blockIdx.x * 128;
    const int ng = blockIdx.y * 128;

    f32x4 acc[4][4];
#pragma unroll
    for (int nt = 0; nt < 4; ++nt) {
        const float bv = bf2f(bias[ng + wn*64 + nt*16 + l16]);
#pragma unroll
        for (int mt = 0; mt < 4; ++mt) acc[mt][nt] = (f32x4){bv, bv, bv, bv};
    }

    const int row = tid >> 2, ch = (tid & 3) * 8;
    for (int k0 = 0; k0 < D_MODEL; k0 += 32) {
        __syncthreads();
        const short* ga0 = X  + (size_t)(m0 + row)      * D_MODEL + k0 + ch;
        const short* ga1 = X  + (size_t)(m0 + 64 + row) * D_MODEL + k0 + ch;
        const short* gb0 = Wt + (size_t)(ng + row)      * D_MODEL + k0 + ch;
        const short* gb1 = Wt + (size_t)(ng + 64 + row) * D_MODEL + k0 + ch;
#ifdef HAS_GLD
        GLD16(ga0, &Als[tid * 8]);
        GLD16(ga1, &Als[2048 + tid * 8]);
        GLD16(gb0, &Bls[tid * 8]);
        GLD16(gb1, &Bls[2048 + tid * 8]);
#else
        short8 r0 = *(const short8*)ga0, r1 = *(const short8*)ga1;
        short8 r2 = *(const short8*)gb0, r3 = *(const short8*)gb1;
        *(short8*)&Als[tid * 8] = r0;  *(short8*)&Als[2048 + tid * 8] = r1;
        *(short8*)&Bls[tid * 8] = r2;  *(short8*)&Bls[2048 + tid * 8] = r3;
#endif
        __syncthreads();

        short8 a[4], b[4];
#pragma unroll
        for (int mt = 0; mt < 4; ++mt)
            a[mt] = *(const short8*)&Als[(wm*64 + mt*16 + l16) * 32 + quad*8];
#pragma unroll
        for (int nt = 0; nt < 4; ++nt)
            b[nt] = *(const short8*)&Bls[(wn*64 + nt*16 + l16) * 32 + quad*8];
#pragma unroll
        for (int mt = 0; mt < 4; ++mt)
#pragma unroll
        for (int nt = 0; nt < 4; ++nt)
            acc[mt][nt] = __builtin_amdgcn_mfma_f32_16x16x32_bf16(a[mt], b[nt], acc[mt][nt], 0, 0, 0);
    }

    const int seg = blockIdx.y / 6;   // 0=q, 1=k, 2=v
    if (seg < 2) {
        short* out = seg ? kb : qb;
        const int nl = ng - seg * 768;
#pragma unroll
        for (int mt = 0; mt < 4; ++mt)
#pragma unroll
        for (int nt = 0; nt < 4; ++nt) {
            const int n = nl + wn*64 + nt*16 + l16;
#pragma unroll
            for (int r = 0; r < 4; ++r) {
                const int m = m0 + wm*64 + mt*16 + quad*4 + r;
                out[(size_t)m * D_MODEL + n] = f2bf(acc[mt][nt][r]);
            }
        }
    } else {
#pragma unroll
        for (int nt = 0; nt < 4; ++nt) {
            const int nv = ng - 1536 + wn*64 + nt*16 + l16;
            const int h = nv >> 6, d = nv & 63;
#pragma unroll
            for (int mt = 0; mt < 4; ++mt) {
                const int m = m0 + wm*64 + mt*16 + quad*4;
                union { _Float16 h4[4]; int2 v; } u;
#pragma unroll
                for (int r = 0; r < 4; ++r) u.h4[r] = (_Float16)acc[mt][nt][r];
                *(int2*)&Vt[((size_t)((m >> 11) * NHEADS + h) * HD + d) * SEQ + (m & (SEQ-1))] = u.v;
            }
        }
    }
}

// ---------------------------------------------------------------------------
// Output projection, 64x64 tiles (grid 64x12 = 768 blocks for occupancy).
// ---------------------------------------------------------------------------
__global__ __launch_bounds__(256) void out_gemm(const short* __restrict__ X,
                                                const short* __restrict__ Wt,
                                                const short* __restrict__ bias,
                                                void* __restrict__ outv,
                                                const int* __restrict__ flag)
{
    __shared__ short Als[64 * 32];
    __shared__ short Bls[64 * 32];

    const int tid = threadIdx.x;
    const int wave = tid >> 6, lane = tid & 63;
    const int quad = lane >> 4, l16 = lane & 15;
    const int m0 = blockIdx.x * 64;
    const int n0 = blockIdx.y * 64;

    f32x4 acc[4];
#pragma unroll
    for (int nt = 0; nt < 4; ++nt) {
        const float bv = bf2f(bias[n0 + nt*16 + l16]);
        acc[nt] = (f32x4){bv, bv, bv, bv};
    }

    const int row = tid >> 2, ch = (tid & 3) * 8;
    for (int k0 = 0; k0 < D_MODEL; k0 += 32) {
        __syncthreads();
        const short* ga = X  + (size_t)(m0 + row) * D_MODEL + k0 + ch;
        const short* gb = Wt + (size_t)(n0 + row) * D_MODEL + k0 + ch;
#ifdef HAS_GLD
        GLD16(ga, &Als[row * 32 + ch]);
        GLD16(gb, &Bls[row * 32 + ch]);
#else
        short8 r0 = *(const short8*)ga, r1 = *(const short8*)gb;
        *(short8*)&Als[row * 32 + ch] = r0;
        *(short8*)&Bls[row * 32 + ch] = r1;
#endif
        __syncthreads();

        short8 a = *(const short8*)&Als[(wave*16 + l16) * 32 + quad*8];
#pragma unroll
        for (int nt = 0; nt < 4; ++nt) {
            short8 b = *(const short8*)&Bls[(nt*16 + l16) * 32 + quad*8];
            acc[nt] = __builtin_amdgcn_mfma_f32_16x16x32_bf16(a, b, acc[nt], 0, 0, 0);
        }
    }

    const bool outf32 = (*flag != 0);
#pragma unroll
    for (int nt = 0; nt < 4; ++nt) {
        const int n = n0 + nt*16 + l16;
#pragma unroll
        for (int r = 0; r < 4; ++r) {
            const int m = m0 + wave*16 + quad*4 + r;
            const size_t idx = (size_t)m * D_MODEL + n;
            if (outf32) ((float*)outv)[idx] = acc[nt][r];
            else        ((short*)outv)[idx] = f2bf(acc[nt][r]);
        }
    }
}

// ---------------------------------------------------------------------------
// In-block split-K flash attention. Block = 256 thr = 4 waves; all waves share
// the same 32 queries, each wave owns a 512-key quarter (8 tiles of 64).
// Partial (O, m, l) per wave combined in-block via LDS at the end.
// Softmax in exp2 domain. K/Vt frags direct from global (L1/L2 dedup).
// Grid = 64 x 24 = 1536 blocks -> ~4 waves/SIMD resident (LDS ~35 KB).
// ---------------------------------------------------------------------------
#define LSTR 72
#define DSTR 68
#define SC_LOG2 0.18033688f   // (1/8) * log2(e)
__global__ __launch_bounds__(256) void attn_mfma(const short* __restrict__ q,
                                                 const short* __restrict__ k,
                                                 const _Float16* __restrict__ Vt,
                                                 short* __restrict__ ctx)
{
    // union: P-scratch (loop phase) / partial-O + ml (combine phase)
    __shared__ __align__(16) char shraw[4*32*DSTR*4 + 4*64*4];   // 35840 B
    _Float16* Pls = (_Float16*)shraw;                 // wave w: + w*32*LSTR
    float*    Ow  = (float*)shraw;                    // wave w: + w*32*DSTR
    float*    ml  = (float*)(shraw + 4*32*DSTR*4);    // [w][q][2]

    const int tid  = threadIdx.x;
    const int wave = tid >> 6, lane = tid & 63;
    const int quad = lane >> 4, l16 = lane & 15;
    const int bh = blockIdx.y;
    const int b = bh / NHEADS, h = bh % NHEADS;
    const size_t bS = (size_t)b * SEQ;
    const int q0 = blockIdx.x * 32;

    _Float16* myP = Pls + wave * 32 * LSTR;
    const _Float16* vbase = Vt + (size_t)bh * HD * SEQ;

    short8 qf[2][2];
#pragma unroll
    for (int qg = 0; qg < 2; ++qg)
#pragma unroll
    for (int k0h = 0; k0h < 2; ++k0h)
        qf[qg][k0h] = *(const short8*)(q + (bS + q0 + qg*16 + l16) * D_MODEL
                                         + h*HD + k0h*32 + quad*8);

    float m_[2] = { -1e30f, -1e30f }, l_[2] = { 0.f, 0.f };
    f32x4 o[2][4];
#pragma unroll
    for (int qg = 0; qg < 2; ++qg)
#pragma unroll
    for (int t = 0; t < 4; ++t) o[qg][t] = (f32x4){0.f, 0.f, 0.f, 0.f};

    for (int jt = 0; jt < 8; ++jt) {
        const int j0 = wave * 512 + jt * 64;

        short8 kf[4][2];
#pragma unroll
        for (int t = 0; t < 4; ++t)
#pragma unroll
        for (int k0h = 0; k0h < 2; ++k0h)
            kf[t][k0h] = *(const short8*)(k + (bS + j0 + t*16 + l16) * D_MODEL
                                            + h*HD + k0h*32 + quad*8);
        half8 vf[4][2];
#pragma unroll
        for (int t = 0; t < 4; ++t)
#pragma unroll
        for (int k0h = 0; k0h < 2; ++k0h)
            vf[t][k0h] = *(const half8*)(vbase + (size_t)(t*16 + l16) * SEQ
                                               + j0 + k0h*32 + quad*8);

        // ---- S^T = K * Q^T ----
        f32x4 s[2][4];
#pragma unroll
        for (int qg = 0; qg < 2; ++qg)
#pragma unroll
        for (int t = 0; t < 4; ++t) s[qg][t] = (f32x4){0.f, 0.f, 0.f, 0.f};
#pragma unroll
        for (int k0h = 0; k0h < 2; ++k0h)
#pragma unroll
        for (int t = 0; t < 4; ++t)
#pragma unroll
        for (int qg = 0; qg < 2; ++qg)
            s[qg][t] = __builtin_amdgcn_mfma_f32_16x16x32_bf16(kf[t][k0h], qf[qg][k0h], s[qg][t], 0, 0, 0);

        // ---- online softmax, exp2 domain (query = l16 col) ----
#pragma unroll
        for (int qg = 0; qg < 2; ++qg) {
            float p[4][4];
            float mx = -1e30f;
#pragma unroll
            for (int t = 0; t < 4; ++t)
#pragma unroll
            for (int r = 0; r < 4; ++r) {
                p[t][r] = s[qg][t][r] * SC_LOG2;
                mx = fmaxf(mx, p[t][r]);
            }
            mx = fmaxf(mx, __shfl_xor(mx, 16));
            mx = fmaxf(mx, __shfl_xor(mx, 32));
            const float mn = fmaxf(m_[qg], mx);
            const float al = exp2f(m_[qg] - mn);
            float rs = 0.f;
#pragma unroll
            for (int t = 0; t < 4; ++t)
#pragma unroll
            for (int r = 0; r < 4; ++r) {
                p[t][r] = exp2f(p[t][r] - mn);
                rs += p[t][r];
            }
            rs += __shfl_xor(rs, 16);
            rs += __shfl_xor(rs, 32);
            l_[qg] = l_[qg] * al + rs;
            m_[qg] = mn;
#pragma unroll
            for (int t = 0; t < 4; ++t) {
                o[qg][t][0] *= al; o[qg][t][1] *= al; o[qg][t][2] *= al; o[qg][t][3] *= al;
                union { _Float16 h4[4]; int2 v; } u4;
#pragma unroll
                for (int r = 0; r < 4; ++r) u4.h4[r] = (_Float16)p[t][r];
                *(int2*)&myP[(qg*16 + l16) * LSTR + t*16 + quad*4] = u4.v;
            }
        }

        // ---- O^T += V^T * P^T ----
#pragma unroll
        for (int k0h = 0; k0h < 2; ++k0h) {
            half8 pf[2];
#pragma unroll
            for (int qg = 0; qg < 2; ++qg)
                pf[qg] = *(half8*)&myP[(qg*16 + l16) * LSTR + k0h*32 + quad*8];
#pragma unroll
            for (int t = 0; t < 4; ++t)
#pragma unroll
            for (int qg = 0; qg < 2; ++qg)
                o[qg][t] = __builtin_amdgcn_mfma_f32_16x16x32_f16(vf[t][k0h], pf[qg], o[qg][t], 0, 0, 0);
        }
    }

    // ---- write per-wave partials (Pls no longer needed after barrier) ----
    __syncthreads();
#pragma unroll
    for (int qg = 0; qg < 2; ++qg) {
#pragma unroll
        for (int t = 0; t < 4; ++t)
            *(f32x4*)&Ow[wave*32*DSTR + (qg*16 + l16)*DSTR + t*16 + quad*4] = o[qg][t];
        if (quad == 0) {
            float2 p2 = { m_[qg], l_[qg] };
            *(float2*)&ml[wave*64 + (qg*16 + l16)*2] = p2;
        }
    }
    __syncthreads();

    // ---- in-block combine of the 4 key-quarter partials ----
    {
        const int qq = tid >> 3, dg = tid & 7;
        float mi[4], li[4], mmax = -1e30f;
#pragma unroll
        for (int i = 0; i < 4; ++i) {
            mi[i] = ml[i*64 + qq*2];
            li[i] = ml[i*64 + qq*2 + 1];
            mmax = fmaxf(mmax, mi[i]);
        }
        float wgt[4], wsum = 0.f;
#pragma unroll
        for (int i = 0; i < 4; ++i) {
            wgt[i] = exp2f(mi[i] - mmax);
            wsum += wgt[i] * li[i];
        }
        const float inv = 1.0f / wsum;
        union { short s8[8]; int4 v; } u;
#pragma unroll
        for (int d = 0; d < 8; ++d) {
            float a = 0.f;
#pragma unroll
            for (int i = 0; i < 4; ++i)
                a += wgt[i] * Ow[i*32*DSTR + qq*DSTR + dg*8 + d];
            u.s8[d] = f2bf(a * inv);
        }
        *(int4*)(ctx + (bS + q0 + qq) * D_MODEL + h*HD + dg*8) = u.v;
    }
}

// ---------------------------------------------------------------------------
extern "C" void kernel_launch(void* const* d_in, const int* in_sizes, int n_in,
                              void* d_out, int out_size, void* d_ws, size_t ws_size,
                              hipStream_t stream)
{
    int* flag = (int*)d_ws;
    short* xc = (short*)((char*)d_ws + 64);
    short* Wt = xc + NX;                 // 4 transposed weights q|k|v|o
    short* bc = Wt + 4 * NW;             // biases q|k|v|o
    short* qb = bc + 4 * D_MODEL;
    short* kb = qb + NX;
    _Float16* Vt = (_Float16*)(kb + NX); // [24][64][2048] f16
    short* cb = (short*)(Vt + NX);

    detect_and_bias<<<1, 256, 0, stream>>>((const short*)d_in[0], flag,
                                           d_in[2], d_in[4], d_in[6], d_in[8], bc);
    conv_x4<<<(int)(NX/4 + 255) / 256, 256, 0, stream>>>(d_in[0], xc, (int)(NX/4), flag);
    conv_wt<<<dim3(12, 12, 4), 256, 0, stream>>>(d_in[1], d_in[3], d_in[5], d_in[7], Wt, flag);

    qkv_gemm<<<dim3(NTOK/128, 2304/128), 256, 0, stream>>>(xc, Wt, bc, qb, kb, Vt);

    attn_mfma<<<dim3(SEQ/32, BATCH*NHEADS), 256, 0, stream>>>(qb, kb, Vt, cb);

    out_gemm<<<dim3(NTOK/64, D_MODEL/64), 256, 0, stream>>>(cb, Wt + 3*NW, bc + 3*D_MODEL, d_out, flag);
}

// Round 6
// 211.451 us; speedup vs baseline: 15.7530x; 1.1279x over previous
//
#include <hip/hip_runtime.h>
#include <hip/hip_bf16.h>
#include <hip/hip_fp16.h>

#define D_MODEL 768
#define NHEADS  12
#define HD      64
#define BATCH   2
#define SEQ     2048
#define NTOK    (BATCH*SEQ)   // 4096
#define NX      ((size_t)NTOK * D_MODEL)     // 3,145,728
#define NW      ((size_t)D_MODEL * D_MODEL)  // 589,824

typedef __attribute__((ext_vector_type(8))) short    short8;
typedef __attribute__((ext_vector_type(8))) _Float16 half8;
typedef __attribute__((ext_vector_type(4))) float    f32x4;

__device__ __forceinline__ float bf2f(short s) {
    union { unsigned u; float f; } c;
    c.u = ((unsigned)(unsigned short)s) << 16;
    return c.f;
}
__device__ __forceinline__ short f2bf(float f) {
    __hip_bfloat16 h = __float2bfloat16(f);
    return *(short*)&h;
}

#ifdef __has_builtin
#if __has_builtin(__builtin_amdgcn_global_load_lds)
#define HAS_GLD 1
#endif
#endif
#ifdef HAS_GLD
#define GLD16(gp, lp) __builtin_amdgcn_global_load_lds( \
    (const __attribute__((address_space(1))) void*)(gp), \
    (__attribute__((address_space(3))) void*)(lp), 16, 0, 0)
#endif

// ---------------------------------------------------------------------------
// Dtype detect (1 = fp32 inputs) + bias conversion, one launch.
// ---------------------------------------------------------------------------
__global__ void detect_and_bias(const short* __restrict__ x, int* __restrict__ flag,
                                const void* __restrict__ b0, const void* __restrict__ b1,
                                const void* __restrict__ b2, const void* __restrict__ b3,
                                short* __restrict__ dst)
{
    __shared__ int red[256];
    const int tid = threadIdx.x;
    int maxe = 0;
    for (int i = tid; i < 4096; i += 256) {
        int e = ((unsigned short)x[i] >> 7) & 0xFF;
        maxe = max(maxe, e);
    }
    red[tid] = maxe;
    __syncthreads();
    for (int s = 128; s > 0; s >>= 1) {
        if (tid < s) red[tid] = max(red[tid], red[tid + s]);
        __syncthreads();
    }
    const bool isf = (red[0] > 140);
    if (tid == 0) *flag = isf ? 1 : 0;
    const void* srcs[4] = { b0, b1, b2, b3 };
    for (int z = 0; z < 4; ++z)
        for (int i = tid; i < D_MODEL; i += 256) {
            short o = isf ? f2bf(((const float*)srcs[z])[i]) : ((const short*)srcs[z])[i];
            dst[z * D_MODEL + i] = o;
        }
}

__global__ void conv_x4(const void* __restrict__ src, short* __restrict__ dst,
                        int n4, const int* __restrict__ flag) {
    const int i = blockIdx.x * 256 + threadIdx.x;
    if (i >= n4) return;
    if (*flag) {
        float4 f = ((const float4*)src)[i];
        short4 o = { f2bf(f.x), f2bf(f.y), f2bf(f.z), f2bf(f.w) };
        ((short4*)dst)[i] = o;
    } else {
        ((short4*)dst)[i] = ((const short4*)src)[i];
    }
}

// Fused convert+transpose of the 4 weight matrices: Wt[n][k] = W[k][n], bf16.
__global__ __launch_bounds__(256) void conv_wt(const void* __restrict__ w0,
                                               const void* __restrict__ w1,
                                               const void* __restrict__ w2,
                                               const void* __restrict__ w3,
                                               short* __restrict__ wt,
                                               const int* __restrict__ flag)
{
    __shared__ float T[64][65];
    const int z = blockIdx.z;
    const void* src = (z == 0) ? w0 : (z == 1) ? w1 : (z == 2) ? w2 : w3;
    const int k0 = blockIdx.x * 64, n0 = blockIdx.y * 64;
    const int a = threadIdx.x & 15, b = threadIdx.x >> 4;
    const bool isf = (*flag != 0);
#pragma unroll
    for (int u = 0; u < 4; ++u) {
        const int kr = (b & 3) + 4 * u + 16 * (b >> 2);
        if (isf) {
            float4 f = *(const float4*)((const float*)src + (size_t)(k0 + kr) * D_MODEL + n0 + a * 4);
            T[kr][a*4+0] = f.x; T[kr][a*4+1] = f.y; T[kr][a*4+2] = f.z; T[kr][a*4+3] = f.w;
        } else {
            short4 s = *(const short4*)((const short*)src + (size_t)(k0 + kr) * D_MODEL + n0 + a * 4);
            T[kr][a*4+0] = bf2f(s.x); T[kr][a*4+1] = bf2f(s.y); T[kr][a*4+2] = bf2f(s.z); T[kr][a*4+3] = bf2f(s.w);
        }
    }
    __syncthreads();
#pragma unroll
    for (int u = 0; u < 4; ++u) {
        const int nr = (b & 3) + 4 * u + 16 * (b >> 2);
        short4 o = { f2bf(T[a*4+0][nr]), f2bf(T[a*4+1][nr]),
                     f2bf(T[a*4+2][nr]), f2bf(T[a*4+3][nr]) };
        *(short4*)(wt + (size_t)z * NW + (size_t)(n0 + nr) * D_MODEL + k0 + a * 4) = o;
    }
}

// ---------------------------------------------------------------------------
// Fused QKV GEMM: OUT[4096][2304] = X @ [Wq|Wk|Wv] + bias. 128x128 tile,
// BK=32, GLD16 staging. V segment stored via LDS transpose -> Vt f16
// [bh][dim][SEQ] with coalesced 16B stores (no 4KB-stride scatter).
// ---------------------------------------------------------------------------
__global__ __launch_bounds__(256) void qkv_gemm(const short* __restrict__ X,
                                                const short* __restrict__ Wt,
                                                const short* __restrict__ bias,
                                                short* __restrict__ qb,
                                                short* __restrict__ kb,
                                                _Float16* __restrict__ Vt)
{
    __shared__ __align__(16) char shbuf[17664];
    short* Als = (short*)shbuf;            // 128*32 shorts = 8 KB
    short* Bls = Als + 4096;               // 8 KB
    _Float16* T = (_Float16*)shbuf;        // epilogue: 64*136 f16 = 17408 B

    const int tid = threadIdx.x;
    const int wave = tid >> 6, lane = tid & 63;
    const int quad = lane >> 4, l16 = lane & 15;
    const int wm = wave & 1, wn = wave >> 1;
    const int m0 = blockIdx.x * 128;
    const int ng = blockIdx.y * 128;

    f32x4 acc[4][4];
#pragma unroll
    for (int nt = 0; nt < 4; ++nt) {
        const float bv = bf2f(bias[ng + wn*64 + nt*16 + l16]);
#pragma unroll
        for (int mt = 0; mt < 4; ++mt) acc[mt][nt] = (f32x4){bv, bv, bv, bv};
    }

    const int row = tid >> 2, ch = (tid & 3) * 8;
    for (int k0 = 0; k0 < D_MODEL; k0 += 32) {
        __syncthreads();
        const short* ga0 = X  + (size_t)(m0 + row)      * D_MODEL + k0 + ch;
        const short* ga1 = X  + (size_t)(m0 + 64 + row) * D_MODEL + k0 + ch;
        const short* gb0 = Wt + (size_t)(ng + row)      * D_MODEL + k0 + ch;
        const short* gb1 = Wt + (size_t)(ng + 64 + row) * D_MODEL + k0 + ch;
#ifdef HAS_GLD
        GLD16(ga0, &Als[tid * 8]);
        GLD16(ga1, &Als[2048 + tid * 8]);
        GLD16(gb0, &Bls[tid * 8]);
        GLD16(gb1, &Bls[2048 + tid * 8]);
#else
        short8 r0 = *(const short8*)ga0, r1 = *(const short8*)ga1;
        short8 r2 = *(const short8*)gb0, r3 = *(const short8*)gb1;
        *(short8*)&Als[tid * 8] = r0;  *(short8*)&Als[2048 + tid * 8] = r1;
        *(short8*)&Bls[tid * 8] = r2;  *(short8*)&Bls[2048 + tid * 8] = r3;
#endif
        __syncthreads();

        short8 a[4], b[4];
#pragma unroll
        for (int mt = 0; mt < 4; ++mt)
            a[mt] = *(const short8*)&Als[(wm*64 + mt*16 + l16) * 32 + quad*8];
#pragma unroll
        for (int nt = 0; nt < 4; ++nt)
            b[nt] = *(const short8*)&Bls[(wn*64 + nt*16 + l16) * 32 + quad*8];
#pragma unroll
        for (int mt = 0; mt < 4; ++mt)
#pragma unroll
        for (int nt = 0; nt < 4; ++nt)
            acc[mt][nt] = __builtin_amdgcn_mfma_f32_16x16x32_bf16(a[mt], b[nt], acc[mt][nt], 0, 0, 0);
    }

    const int seg = blockIdx.y / 6;   // 0=q, 1=k, 2=v
    if (seg < 2) {
        short* out = seg ? kb : qb;
        const int nl = ng - seg * 768;
#pragma unroll
        for (int mt = 0; mt < 4; ++mt)
#pragma unroll
        for (int nt = 0; nt < 4; ++nt) {
            const int n = nl + wn*64 + nt*16 + l16;
#pragma unroll
            for (int r = 0; r < 4; ++r) {
                const int m = m0 + wm*64 + mt*16 + quad*4 + r;
                out[(size_t)m * D_MODEL + n] = f2bf(acc[mt][nt][r]);
            }
        }
    } else {
        // LDS-transpose epilogue: 2 passes of 64 dims x 128 tokens.
        const int batch = m0 >> 11, tokb = m0 & (SEQ - 1);
        __syncthreads();   // all K-loop LDS reads done before reuse
        for (int pass = 0; pass < 2; ++pass) {
            if (wn == pass) {
#pragma unroll
                for (int nt = 0; nt < 4; ++nt) {
                    const int dim_l = nt*16 + l16;
#pragma unroll
                    for (int mt = 0; mt < 4; ++mt) {
                        const int tok_l = wm*64 + mt*16 + quad*4;
                        union { _Float16 h4[4]; int2 v; } u;
#pragma unroll
                        for (int r = 0; r < 4; ++r) u.h4[r] = (_Float16)acc[mt][nt][r];
                        *(int2*)&T[dim_l * 136 + tok_l] = u.v;
                    }
                }
            }
            __syncthreads();
#pragma unroll
            for (int u = 0; u < 4; ++u) {
                const int slot = tid + u * 256;
                const int drow = slot >> 4, chk = slot & 15;
                int4 val = *(const int4*)&T[drow * 136 + chk * 8];
                const int dim_g = ng - 1536 + pass*64 + drow;
                const int h = dim_g >> 6, d = dim_g & 63;
                *(int4*)(Vt + ((size_t)(batch * NHEADS + h) * HD + d) * SEQ + tokb + chk*8) = val;
            }
            if (pass == 0) __syncthreads();
        }
    }
}

// ---------------------------------------------------------------------------
// Output projection, 64x64 tiles (grid 64x12 = 768 blocks).
// ---------------------------------------------------------------------------
__global__ __launch_bounds__(256) void out_gemm(const short* __restrict__ X,
                                                const short* __restrict__ Wt,
                                                const short* __restrict__ bias,
                                                void* __restrict__ outv,
                                                const int* __restrict__ flag)
{
    __shared__ short Als[64 * 32];
    __shared__ short Bls[64 * 32];

    const int tid = threadIdx.x;
    const int wave = tid >> 6, lane = tid & 63;
    const int quad = lane >> 4, l16 = lane & 15;
    const int m0 = blockIdx.x * 64;
    const int n0 = blockIdx.y * 64;

    f32x4 acc[4];
#pragma unroll
    for (int nt = 0; nt < 4; ++nt) {
        const float bv = bf2f(bias[n0 + nt*16 + l16]);
        acc[nt] = (f32x4){bv, bv, bv, bv};
    }

    const int row = tid >> 2, ch = (tid & 3) * 8;
    for (int k0 = 0; k0 < D_MODEL; k0 += 32) {
        __syncthreads();
        const short* ga = X  + (size_t)(m0 + row) * D_MODEL + k0 + ch;
        const short* gb = Wt + (size_t)(n0 + row) * D_MODEL + k0 + ch;
#ifdef HAS_GLD
        GLD16(ga, &Als[row * 32 + ch]);
        GLD16(gb, &Bls[row * 32 + ch]);
#else
        short8 r0 = *(const short8*)ga, r1 = *(const short8*)gb;
        *(short8*)&Als[row * 32 + ch] = r0;
        *(short8*)&Bls[row * 32 + ch] = r1;
#endif
        __syncthreads();

        short8 a = *(const short8*)&Als[(wave*16 + l16) * 32 + quad*8];
#pragma unroll
        for (int nt = 0; nt < 4; ++nt) {
            short8 b = *(const short8*)&Bls[(nt*16 + l16) * 32 + quad*8];
            acc[nt] = __builtin_amdgcn_mfma_f32_16x16x32_bf16(a, b, acc[nt], 0, 0, 0);
        }
    }

    const bool outf32 = (*flag != 0);
#pragma unroll
    for (int nt = 0; nt < 4; ++nt) {
        const int n = n0 + nt*16 + l16;
#pragma unroll
        for (int r = 0; r < 4; ++r) {
            const int m = m0 + wave*16 + quad*4 + r;
            const size_t idx = (size_t)m * D_MODEL + n;
            if (outf32) ((float*)outv)[idx] = acc[nt][r];
            else        ((short*)outv)[idx] = f2bf(acc[nt][r]);
        }
    }
}

// ---------------------------------------------------------------------------
// Flash attention, LDS-staged + double-buffered. Block = 256 thr = 4 waves,
// 64 queries/block (16 per wave), K/V tiles of 64 keys shared by all waves.
// Staging via GLD16 into XOR-swizzled pad-free LDS (conflict-free b128 reads).
// One __syncthreads per tile; next-tile GLD16s fly during compute.
// LDS = 41 KB -> exactly 3 blocks/CU; grid 768 = exactly 3/CU resident.
// ---------------------------------------------------------------------------
#define PSTR 72
#define SC_LOG2 0.18033688f   // (1/8) * log2(e)
__global__ __launch_bounds__(256) void attn_mfma(const short* __restrict__ q,
                                                 const short* __restrict__ k,
                                                 const _Float16* __restrict__ Vt,
                                                 short* __restrict__ ctx)
{
    __shared__ short    Kls[2][64 * 64];       // swizzled [key][chunk], 8 KB/buf
    __shared__ _Float16 Vls[2][64 * 64];       // swizzled [dim][chunk], 8 KB/buf
    __shared__ _Float16 Pls[4][16 * PSTR];     // per-wave P scratch, 9216 B

    const int tid  = threadIdx.x;
    const int wave = tid >> 6, lane = tid & 63;
    const int quad = lane >> 4, l16 = lane & 15;
    const int bh = blockIdx.y;
    const int b = bh / NHEADS, h = bh % NHEADS;
    const size_t bS = (size_t)b * SEQ;
    const int q0 = blockIdx.x * 64;
    const int myq = q0 + wave * 16 + l16;

    // Q A-frag (row-major global, once per kernel)
    short8 qf[2];
#pragma unroll
    for (int k0h = 0; k0h < 2; ++k0h)
        qf[k0h] = *(const short8*)(q + (bS + myq) * D_MODEL + h*HD + k0h*32 + quad*8);

    // staging slots: s = tid, tid+256; row = s>>3, pchunk = s&7,
    // logical chunk = pchunk ^ (row&7)
    const int s0 = tid, s1 = tid + 256;
    const int kr0 = s0 >> 3, kc0 = (s0 & 7) ^ (kr0 & 7);
    const int kr1 = s1 >> 3, kc1 = (s1 & 7) ^ (kr1 & 7);
    const short*    kg0 = k  + (bS + kr0) * D_MODEL + h*HD + kc0*8;
    const short*    kg1 = k  + (bS + kr1) * D_MODEL + h*HD + kc1*8;
    const _Float16* vg0 = Vt + ((size_t)bh * HD + kr0) * SEQ + kc0*8;
    const _Float16* vg1 = Vt + ((size_t)bh * HD + kr1) * SEQ + kc1*8;

#ifdef HAS_GLD
#define STAGE(buf, j0) do { \
        GLD16(kg0 + (size_t)(j0) * D_MODEL, &Kls[buf][s0 * 8]); \
        GLD16(kg1 + (size_t)(j0) * D_MODEL, &Kls[buf][s1 * 8]); \
        GLD16(vg0 + (j0),                   &Vls[buf][s0 * 8]); \
        GLD16(vg1 + (j0),                   &Vls[buf][s1 * 8]); \
    } while (0)
#else
#define STAGE(buf, j0) do { \
        short8 a_ = *(const short8*)(kg0 + (size_t)(j0) * D_MODEL); \
        short8 b_ = *(const short8*)(kg1 + (size_t)(j0) * D_MODEL); \
        half8  c_ = *(const half8*)(vg0 + (j0)); \
        half8  d_ = *(const half8*)(vg1 + (j0)); \
        *(short8*)&Kls[buf][s0 * 8] = a_;  *(short8*)&Kls[buf][s1 * 8] = b_; \
        *(half8*)&Vls[buf][s0 * 8] = c_;   *(half8*)&Vls[buf][s1 * 8] = d_; \
    } while (0)
#endif

    float m_ = -1e30f, l_ = 0.f;
    f32x4 o[4];
#pragma unroll
    for (int t = 0; t < 4; ++t) o[t] = (f32x4){0.f, 0.f, 0.f, 0.f};

    STAGE(0, 0);           // preload tile 0
    __syncthreads();       // tile 0 landed

    for (int jt = 0; jt < SEQ / 64; ++jt) {
        const int cur = jt & 1;
        if (jt + 1 < SEQ / 64) STAGE(cur ^ 1, (jt + 1) * 64);

        // ---- S^T = K * Q^T : D[m=key][n=q(l16)] ----
        f32x4 s4[4];
#pragma unroll
        for (int t = 0; t < 4; ++t) s4[t] = (f32x4){0.f, 0.f, 0.f, 0.f};
#pragma unroll
        for (int k0h = 0; k0h < 2; ++k0h)
#pragma unroll
        for (int t = 0; t < 4; ++t) {
            const int krow = t*16 + l16;
            short8 kf = *(const short8*)&Kls[cur][krow*64 + (((k0h*4 + quad) ^ (krow & 7)) * 8)];
            s4[t] = __builtin_amdgcn_mfma_f32_16x16x32_bf16(kf, qf[k0h], s4[t], 0, 0, 0);
        }

        // ---- online softmax (exp2 domain), col = l16 = my query ----
        float p[4][4];
        float mx = -1e30f;
#pragma unroll
        for (int t = 0; t < 4; ++t)
#pragma unroll
        for (int r = 0; r < 4; ++r) {
            p[t][r] = s4[t][r] * SC_LOG2;
            mx = fmaxf(mx, p[t][r]);
        }
        mx = fmaxf(mx, __shfl_xor(mx, 16));
        mx = fmaxf(mx, __shfl_xor(mx, 32));
        const float mn = fmaxf(m_, mx);
        const float al = exp2f(m_ - mn);
        float rs = 0.f;
#pragma unroll
        for (int t = 0; t < 4; ++t)
#pragma unroll
        for (int r = 0; r < 4; ++r) {
            p[t][r] = exp2f(p[t][r] - mn);
            rs += p[t][r];
        }
        rs += __shfl_xor(rs, 16);
        rs += __shfl_xor(rs, 32);
        l_ = l_ * al + rs;
        m_ = mn;
#pragma unroll
        for (int t = 0; t < 4; ++t) {
            o[t][0] *= al; o[t][1] *= al; o[t][2] *= al; o[t][3] *= al;
            union { _Float16 h4[4]; int2 v; } u4;
#pragma unroll
            for (int r = 0; r < 4; ++r) u4.h4[r] = (_Float16)p[t][r];
            *(int2*)&Pls[wave][l16 * PSTR + t*16 + quad*4] = u4.v;
        }

        // ---- O^T += V^T * P^T : D[m=dim][n=q] ----
#pragma unroll
        for (int k0h = 0; k0h < 2; ++k0h) {
            half8 pf = *(half8*)&Pls[wave][l16 * PSTR + k0h*32 + quad*8];
#pragma unroll
            for (int t = 0; t < 4; ++t) {
                const int vrow = t*16 + l16;
                half8 vf = *(const half8*)&Vls[cur][vrow*64 + (((k0h*4 + quad) ^ (vrow & 7)) * 8)];
                o[t] = __builtin_amdgcn_mfma_f32_16x16x32_f16(vf, pf, o[t], 0, 0, 0);
            }
        }

        __syncthreads();   // all waves done with buf cur; next-tile loads drained
    }

    // ---- normalize + packed bf16 stores ----
    const float inv = 1.0f / l_;
    const size_t rowp = (bS + myq) * D_MODEL + h*HD;
#pragma unroll
    for (int t = 0; t < 4; ++t) {
        union { short s4v[4]; int2 v; } u4;
#pragma unroll
        for (int r = 0; r < 4; ++r) u4.s4v[r] = f2bf(o[t][r] * inv);
        *(int2*)(ctx + rowp + t*16 + quad*4) = u4.v;
    }
#undef STAGE
}

// ---------------------------------------------------------------------------
extern "C" void kernel_launch(void* const* d_in, const int* in_sizes, int n_in,
                              void* d_out, int out_size, void* d_ws, size_t ws_size,
                              hipStream_t stream)
{
    int* flag = (int*)d_ws;
    short* xc = (short*)((char*)d_ws + 64);
    short* Wt = xc + NX;                 // 4 transposed weights q|k|v|o
    short* bc = Wt + 4 * NW;             // biases q|k|v|o
    short* qb = bc + 4 * D_MODEL;
    short* kb = qb + NX;
    _Float16* Vt = (_Float16*)(kb + NX); // [24][64][2048] f16
    short* cb = (short*)(Vt + NX);

    detect_and_bias<<<1, 256, 0, stream>>>((const short*)d_in[0], flag,
                                           d_in[2], d_in[4], d_in[6], d_in[8], bc);
    conv_x4<<<(int)(NX/4 + 255) / 256, 256, 0, stream>>>(d_in[0], xc, (int)(NX/4), flag);
    conv_wt<<<dim3(12, 12, 4), 256, 0, stream>>>(d_in[1], d_in[3], d_in[5], d_in[7], Wt, flag);

    qkv_gemm<<<dim3(NTOK/128, 2304/128), 256, 0, stream>>>(xc, Wt, bc, qb, kb, Vt);

    attn_mfma<<<dim3(SEQ/64, BATCH*NHEADS), 256, 0, stream>>>(qb, kb, Vt, cb);

    out_gemm<<<dim3(NTOK/64, D_MODEL/64), 256, 0, stream>>>(cb, Wt + 3*NW, bc + 3*D_MODEL, d_out, flag);
}

// Round 7
// 204.478 us; speedup vs baseline: 16.2903x; 1.0341x over previous
//
#include <hip/hip_runtime.h>
#include <hip/hip_bf16.h>
#include <hip/hip_fp16.h>

#define D_MODEL 768
#define NHEADS  12
#define HD      64
#define BATCH   2
#define SEQ     2048
#define NTOK    (BATCH*SEQ)   // 4096
#define NX      ((size_t)NTOK * D_MODEL)     // 3,145,728
#define NW      ((size_t)D_MODEL * D_MODEL)  // 589,824
#define SC_LOG2 0.18033688f   // (1/8) * log2(e), folded into Wq/bq

typedef __attribute__((ext_vector_type(8))) short    short8;
typedef __attribute__((ext_vector_type(8))) _Float16 half8;
typedef __attribute__((ext_vector_type(4))) float    f32x4;

__device__ __forceinline__ float bf2f(short s) {
    union { unsigned u; float f; } c;
    c.u = ((unsigned)(unsigned short)s) << 16;
    return c.f;
}
__device__ __forceinline__ short f2bf(float f) {
    __hip_bfloat16 h = __float2bfloat16(f);
    return *(short*)&h;
}

#ifdef __has_builtin
#if __has_builtin(__builtin_amdgcn_global_load_lds)
#define HAS_GLD 1
#endif
#endif
#ifdef HAS_GLD
#define GLD16(gp, lp) __builtin_amdgcn_global_load_lds( \
    (const __attribute__((address_space(1))) void*)(gp), \
    (__attribute__((address_space(3))) void*)(lp), 16, 0, 0)
#endif

// ---------------------------------------------------------------------------
// Dtype detect (1 = fp32 inputs) + bias conversion (bq pre-scaled by SC_LOG2).
// ---------------------------------------------------------------------------
__global__ void detect_and_bias(const short* __restrict__ x, int* __restrict__ flag,
                                const void* __restrict__ b0, const void* __restrict__ b1,
                                const void* __restrict__ b2, const void* __restrict__ b3,
                                short* __restrict__ dst)
{
    __shared__ int red[256];
    const int tid = threadIdx.x;
    int maxe = 0;
    for (int i = tid; i < 4096; i += 256) {
        int e = ((unsigned short)x[i] >> 7) & 0xFF;
        maxe = max(maxe, e);
    }
    red[tid] = maxe;
    __syncthreads();
    for (int s = 128; s > 0; s >>= 1) {
        if (tid < s) red[tid] = max(red[tid], red[tid + s]);
        __syncthreads();
    }
    const bool isf = (red[0] > 140);
    if (tid == 0) *flag = isf ? 1 : 0;
    const void* srcs[4] = { b0, b1, b2, b3 };
    for (int z = 0; z < 4; ++z) {
        const float sc = (z == 0) ? SC_LOG2 : 1.0f;
        for (int i = tid; i < D_MODEL; i += 256) {
            float v = isf ? ((const float*)srcs[z])[i] : bf2f(((const short*)srcs[z])[i]);
            dst[z * D_MODEL + i] = f2bf(v * sc);
        }
    }
}

__global__ void conv_x4(const void* __restrict__ src, short* __restrict__ dst,
                        int n4, const int* __restrict__ flag) {
    const int i = blockIdx.x * 256 + threadIdx.x;
    if (i >= n4) return;
    if (*flag) {
        float4 f = ((const float4*)src)[i];
        short4 o = { f2bf(f.x), f2bf(f.y), f2bf(f.z), f2bf(f.w) };
        ((short4*)dst)[i] = o;
    } else {
        ((short4*)dst)[i] = ((const short4*)src)[i];
    }
}

// Fused convert+transpose of the 4 weight matrices: Wt[n][k] = W[k][n], bf16.
// Wq (z==0) pre-scaled by SC_LOG2 so QK logits emerge in exp2 domain.
__global__ __launch_bounds__(256) void conv_wt(const void* __restrict__ w0,
                                               const void* __restrict__ w1,
                                               const void* __restrict__ w2,
                                               const void* __restrict__ w3,
                                               short* __restrict__ wt,
                                               const int* __restrict__ flag)
{
    __shared__ float T[64][65];
    const int z = blockIdx.z;
    const void* src = (z == 0) ? w0 : (z == 1) ? w1 : (z == 2) ? w2 : w3;
    const float sc = (z == 0) ? SC_LOG2 : 1.0f;
    const int k0 = blockIdx.x * 64, n0 = blockIdx.y * 64;
    const int a = threadIdx.x & 15, b = threadIdx.x >> 4;
    const bool isf = (*flag != 0);
#pragma unroll
    for (int u = 0; u < 4; ++u) {
        const int kr = (b & 3) + 4 * u + 16 * (b >> 2);
        if (isf) {
            float4 f = *(const float4*)((const float*)src + (size_t)(k0 + kr) * D_MODEL + n0 + a * 4);
            T[kr][a*4+0] = f.x; T[kr][a*4+1] = f.y; T[kr][a*4+2] = f.z; T[kr][a*4+3] = f.w;
        } else {
            short4 s = *(const short4*)((const short*)src + (size_t)(k0 + kr) * D_MODEL + n0 + a * 4);
            T[kr][a*4+0] = bf2f(s.x); T[kr][a*4+1] = bf2f(s.y); T[kr][a*4+2] = bf2f(s.z); T[kr][a*4+3] = bf2f(s.w);
        }
    }
    __syncthreads();
#pragma unroll
    for (int u = 0; u < 4; ++u) {
        const int nr = (b & 3) + 4 * u + 16 * (b >> 2);
        short4 o = { f2bf(T[a*4+0][nr] * sc), f2bf(T[a*4+1][nr] * sc),
                     f2bf(T[a*4+2][nr] * sc), f2bf(T[a*4+3][nr] * sc) };
        *(short4*)(wt + (size_t)z * NW + (size_t)(n0 + nr) * D_MODEL + k0 + a * 4) = o;
    }
}

// ---------------------------------------------------------------------------
// Fused QKV GEMM, double-buffered: OUT[4096][2304] = X @ [Wq|Wk|Wv] + bias.
// 128x128 tile, BK=32. GLD16 prefetch of step n+1 issued before computing
// step n; end-of-step barrier drains loads that flew during compute.
// V segment -> Vt f16 [bh][dim][SEQ] via LDS transpose.
// ---------------------------------------------------------------------------
__global__ __launch_bounds__(256) void qkv_gemm(const short* __restrict__ X,
                                                const short* __restrict__ Wt,
                                                const short* __restrict__ bias,
                                                short* __restrict__ qb,
                                                short* __restrict__ kb,
                                                _Float16* __restrict__ Vt)
{
    __shared__ __align__(16) char shbuf[32768];
    short* Als = (short*)shbuf;              // [2][4096]
    short* Bls = (short*)(shbuf + 16384);    // [2][4096]
    _Float16* T = (_Float16*)shbuf;          // epilogue: 64*136 f16 = 17408 B

    const int tid = threadIdx.x;
    const int wave = tid >> 6, lane = tid & 63;
    const int quad = lane >> 4, l16 = lane & 15;
    const int wm = wave & 1, wn = wave >> 1;
    const int m0 = blockIdx.x * 128;
    const int ng = blockIdx.y * 128;

    f32x4 acc[4][4];
#pragma unroll
    for (int nt = 0; nt < 4; ++nt) {
        const float bv = bf2f(bias[ng + wn*64 + nt*16 + l16]);
#pragma unroll
        for (int mt = 0; mt < 4; ++mt) acc[mt][nt] = (f32x4){bv, bv, bv, bv};
    }

    const int row = tid >> 2, ch = (tid & 3) * 8;
#ifdef HAS_GLD
#define QSTAGE(buf, k0) do { \
        GLD16(X  + (size_t)(m0 + row)      * D_MODEL + (k0) + ch, &Als[(buf)*4096 + tid*8]); \
        GLD16(X  + (size_t)(m0 + 64 + row) * D_MODEL + (k0) + ch, &Als[(buf)*4096 + 2048 + tid*8]); \
        GLD16(Wt + (size_t)(ng + row)      * D_MODEL + (k0) + ch, &Bls[(buf)*4096 + tid*8]); \
        GLD16(Wt + (size_t)(ng + 64 + row) * D_MODEL + (k0) + ch, &Bls[(buf)*4096 + 2048 + tid*8]); \
    } while (0)
#else
#define QSTAGE(buf, k0) do { \
        short8 r0 = *(const short8*)(X  + (size_t)(m0 + row)      * D_MODEL + (k0) + ch); \
        short8 r1 = *(const short8*)(X  + (size_t)(m0 + 64 + row) * D_MODEL + (k0) + ch); \
        short8 r2 = *(const short8*)(Wt + (size_t)(ng + row)      * D_MODEL + (k0) + ch); \
        short8 r3 = *(const short8*)(Wt + (size_t)(ng + 64 + row) * D_MODEL + (k0) + ch); \
        *(short8*)&Als[(buf)*4096 + tid*8] = r0;  *(short8*)&Als[(buf)*4096 + 2048 + tid*8] = r1; \
        *(short8*)&Bls[(buf)*4096 + tid*8] = r2;  *(short8*)&Bls[(buf)*4096 + 2048 + tid*8] = r3; \
    } while (0)
#endif

    QSTAGE(0, 0);
    __syncthreads();

    for (int ks = 0; ks < 24; ++ks) {
        const int cur = ks & 1;
        if (ks + 1 < 24) QSTAGE(cur ^ 1, (ks + 1) * 32);

        short8 a[4], b[4];
#pragma unroll
        for (int mt = 0; mt < 4; ++mt)
            a[mt] = *(const short8*)&Als[cur*4096 + (wm*64 + mt*16 + l16) * 32 + quad*8];
#pragma unroll
        for (int nt = 0; nt < 4; ++nt)
            b[nt] = *(const short8*)&Bls[cur*4096 + (wn*64 + nt*16 + l16) * 32 + quad*8];
#pragma unroll
        for (int mt = 0; mt < 4; ++mt)
#pragma unroll
        for (int nt = 0; nt < 4; ++nt)
            acc[mt][nt] = __builtin_amdgcn_mfma_f32_16x16x32_bf16(a[mt], b[nt], acc[mt][nt], 0, 0, 0);

        __syncthreads();
    }
#undef QSTAGE

    const int seg = blockIdx.y / 6;   // 0=q, 1=k, 2=v
    if (seg < 2) {
        short* out = seg ? kb : qb;
        const int nl = ng - seg * 768;
#pragma unroll
        for (int mt = 0; mt < 4; ++mt)
#pragma unroll
        for (int nt = 0; nt < 4; ++nt) {
            const int n = nl + wn*64 + nt*16 + l16;
#pragma unroll
            for (int r = 0; r < 4; ++r) {
                const int m = m0 + wm*64 + mt*16 + quad*4 + r;
                out[(size_t)m * D_MODEL + n] = f2bf(acc[mt][nt][r]);
            }
        }
    } else {
        // LDS-transpose epilogue: 2 passes of 64 dims x 128 tokens.
        const int batch = m0 >> 11, tokb = m0 & (SEQ - 1);
        for (int pass = 0; pass < 2; ++pass) {
            if (wn == pass) {
#pragma unroll
                for (int nt = 0; nt < 4; ++nt) {
                    const int dim_l = nt*16 + l16;
#pragma unroll
                    for (int mt = 0; mt < 4; ++mt) {
                        const int tok_l = wm*64 + mt*16 + quad*4;
                        union { _Float16 h4[4]; int2 v; } u;
#pragma unroll
                        for (int r = 0; r < 4; ++r) u.h4[r] = (_Float16)acc[mt][nt][r];
                        *(int2*)&T[dim_l * 136 + tok_l] = u.v;
                    }
                }
            }
            __syncthreads();
#pragma unroll
            for (int u = 0; u < 4; ++u) {
                const int slot = tid + u * 256;
                const int drow = slot >> 4, chk = slot & 15;
                int4 val = *(const int4*)&T[drow * 136 + chk * 8];
                const int dim_g = ng - 1536 + pass*64 + drow;
                const int h = dim_g >> 6, d = dim_g & 63;
                *(int4*)(Vt + ((size_t)(batch * NHEADS + h) * HD + d) * SEQ + tokb + chk*8) = val;
            }
            if (pass == 0) __syncthreads();
        }
    }
}

// ---------------------------------------------------------------------------
// Output projection, 64x64 tiles, double-buffered staging.
// ---------------------------------------------------------------------------
__global__ __launch_bounds__(256) void out_gemm(const short* __restrict__ X,
                                                const short* __restrict__ Wt,
                                                const short* __restrict__ bias,
                                                void* __restrict__ outv,
                                                const int* __restrict__ flag)
{
    __shared__ short Als[2][2048];
    __shared__ short Bls[2][2048];

    const int tid = threadIdx.x;
    const int wave = tid >> 6, lane = tid & 63;
    const int quad = lane >> 4, l16 = lane & 15;
    const int m0 = blockIdx.x * 64;
    const int n0 = blockIdx.y * 64;

    f32x4 acc[4];
#pragma unroll
    for (int nt = 0; nt < 4; ++nt) {
        const float bv = bf2f(bias[n0 + nt*16 + l16]);
        acc[nt] = (f32x4){bv, bv, bv, bv};
    }

    const int row = tid >> 2, ch = (tid & 3) * 8;
#ifdef HAS_GLD
#define OSTAGE(buf, k0) do { \
        GLD16(X  + (size_t)(m0 + row) * D_MODEL + (k0) + ch, &Als[buf][tid*8]); \
        GLD16(Wt + (size_t)(n0 + row) * D_MODEL + (k0) + ch, &Bls[buf][tid*8]); \
    } while (0)
#else
#define OSTAGE(buf, k0) do { \
        short8 r0 = *(const short8*)(X  + (size_t)(m0 + row) * D_MODEL + (k0) + ch); \
        short8 r1 = *(const short8*)(Wt + (size_t)(n0 + row) * D_MODEL + (k0) + ch); \
        *(short8*)&Als[buf][tid*8] = r0; \
        *(short8*)&Bls[buf][tid*8] = r1; \
    } while (0)
#endif

    OSTAGE(0, 0);
    __syncthreads();

    for (int ks = 0; ks < 24; ++ks) {
        const int cur = ks & 1;
        if (ks + 1 < 24) OSTAGE(cur ^ 1, (ks + 1) * 32);

        short8 a = *(const short8*)&Als[cur][(wave*16 + l16) * 32 + quad*8];
#pragma unroll
        for (int nt = 0; nt < 4; ++nt) {
            short8 b = *(const short8*)&Bls[cur][(nt*16 + l16) * 32 + quad*8];
            acc[nt] = __builtin_amdgcn_mfma_f32_16x16x32_bf16(a, b, acc[nt], 0, 0, 0);
        }
        __syncthreads();
    }
#undef OSTAGE

    const bool outf32 = (*flag != 0);
#pragma unroll
    for (int nt = 0; nt < 4; ++nt) {
        const int n = n0 + nt*16 + l16;
#pragma unroll
        for (int r = 0; r < 4; ++r) {
            const int m = m0 + wave*16 + quad*4 + r;
            const size_t idx = (size_t)m * D_MODEL + n;
            if (outf32) ((float*)outv)[idx] = acc[nt][r];
            else        ((short*)outv)[idx] = f2bf(acc[nt][r]);
        }
    }
}

// ---------------------------------------------------------------------------
// Flash attention, LDS-staged + double-buffered, low-VALU softmax:
//  - logits arrive in exp2 domain (scale folded into Wq/bq)
//  - wave-shared running max; o/l rescale only when it increases (scalar branch)
//  - row-sum l computed on the MFMA pipe with an all-ones A fragment
// Block = 256 thr = 4 waves, 64 q/block, K/V tiles of 64 keys shared by waves.
// ---------------------------------------------------------------------------
#define PSTR 72
__global__ __launch_bounds__(256) void attn_mfma(const short* __restrict__ q,
                                                 const short* __restrict__ k,
                                                 const _Float16* __restrict__ Vt,
                                                 short* __restrict__ ctx)
{
    __shared__ short    Kls[2][64 * 64];       // swizzled [key][chunk], 8 KB/buf
    __shared__ _Float16 Vls[2][64 * 64];       // swizzled [dim][chunk], 8 KB/buf
    __shared__ _Float16 Pls[4][16 * PSTR];     // per-wave P scratch, 9216 B

    const int tid  = threadIdx.x;
    const int wave = tid >> 6, lane = tid & 63;
    const int quad = lane >> 4, l16 = lane & 15;
    const int bh = blockIdx.y;
    const int b = bh / NHEADS, h = bh % NHEADS;
    const size_t bS = (size_t)b * SEQ;
    const int q0 = blockIdx.x * 64;
    const int myq = q0 + wave * 16 + l16;

    short8 qf[2];
#pragma unroll
    for (int k0h = 0; k0h < 2; ++k0h)
        qf[k0h] = *(const short8*)(q + (bS + myq) * D_MODEL + h*HD + k0h*32 + quad*8);

    half8 ones;
#pragma unroll
    for (int j = 0; j < 8; ++j) ones[j] = (_Float16)1.0f;

    const int s0 = tid, s1 = tid + 256;
    const int kr0 = s0 >> 3, kc0 = (s0 & 7) ^ (kr0 & 7);
    const int kr1 = s1 >> 3, kc1 = (s1 & 7) ^ (kr1 & 7);
    const short*    kg0 = k  + (bS + kr0) * D_MODEL + h*HD + kc0*8;
    const short*    kg1 = k  + (bS + kr1) * D_MODEL + h*HD + kc1*8;
    const _Float16* vg0 = Vt + ((size_t)bh * HD + kr0) * SEQ + kc0*8;
    const _Float16* vg1 = Vt + ((size_t)bh * HD + kr1) * SEQ + kc1*8;

#ifdef HAS_GLD
#define STAGE(buf, j0) do { \
        GLD16(kg0 + (size_t)(j0) * D_MODEL, &Kls[buf][s0 * 8]); \
        GLD16(kg1 + (size_t)(j0) * D_MODEL, &Kls[buf][s1 * 8]); \
        GLD16(vg0 + (j0),                   &Vls[buf][s0 * 8]); \
        GLD16(vg1 + (j0),                   &Vls[buf][s1 * 8]); \
    } while (0)
#else
#define STAGE(buf, j0) do { \
        short8 a_ = *(const short8*)(kg0 + (size_t)(j0) * D_MODEL); \
        short8 b_ = *(const short8*)(kg1 + (size_t)(j0) * D_MODEL); \
        half8  c_ = *(const half8*)(vg0 + (j0)); \
        half8  d_ = *(const half8*)(vg1 + (j0)); \
        *(short8*)&Kls[buf][s0 * 8] = a_;  *(short8*)&Kls[buf][s1 * 8] = b_; \
        *(half8*)&Vls[buf][s0 * 8] = c_;   *(half8*)&Vls[buf][s1 * 8] = d_; \
    } while (0)
#endif

    float m_ = -1e30f;
    f32x4 lacc = (f32x4){0.f, 0.f, 0.f, 0.f};
    f32x4 o[4];
#pragma unroll
    for (int t = 0; t < 4; ++t) o[t] = (f32x4){0.f, 0.f, 0.f, 0.f};

    STAGE(0, 0);
    __syncthreads();

    for (int jt = 0; jt < SEQ / 64; ++jt) {
        const int cur = jt & 1;
        if (jt + 1 < SEQ / 64) STAGE(cur ^ 1, (jt + 1) * 64);

        // ---- S^T = K * Q^T (already exp2-domain) ----
        f32x4 s4[4];
#pragma unroll
        for (int t = 0; t < 4; ++t) s4[t] = (f32x4){0.f, 0.f, 0.f, 0.f};
#pragma unroll
        for (int k0h = 0; k0h < 2; ++k0h)
#pragma unroll
        for (int t = 0; t < 4; ++t) {
            const int krow = t*16 + l16;
            short8 kf = *(const short8*)&Kls[cur][krow*64 + (((k0h*4 + quad) ^ (krow & 7)) * 8)];
            s4[t] = __builtin_amdgcn_mfma_f32_16x16x32_bf16(kf, qf[k0h], s4[t], 0, 0, 0);
        }

        // ---- wave-shared online max; rescale only when it increases ----
        float mx = s4[0][0];
#pragma unroll
        for (int t = 0; t < 4; ++t)
#pragma unroll
        for (int r = 0; r < 4; ++r) mx = fmaxf(mx, s4[t][r]);
#pragma unroll
        for (int d = 1; d < 64; d <<= 1) mx = fmaxf(mx, __shfl_xor(mx, d));
        const float mn = fmaxf(m_, mx);
        if (__builtin_amdgcn_readfirstlane((int)(mn > m_))) {
            const float al = exp2f(m_ - mn);
#pragma unroll
            for (int t = 0; t < 4; ++t) {
                o[t][0] *= al; o[t][1] *= al; o[t][2] *= al; o[t][3] *= al;
            }
            lacc[0] *= al; lacc[1] *= al; lacc[2] *= al; lacc[3] *= al;
            m_ = mn;
        }

        // ---- P = exp2(S - m), f16, to per-wave LDS ----
#pragma unroll
        for (int t = 0; t < 4; ++t) {
            union { _Float16 h4[4]; int2 v; } u4;
#pragma unroll
            for (int r = 0; r < 4; ++r) u4.h4[r] = (_Float16)exp2f(s4[t][r] - mn);
            *(int2*)&Pls[wave][l16 * PSTR + t*16 + quad*4] = u4.v;
        }

        // ---- O^T += V^T * P^T ; l += ones * P^T (MFMA pipe) ----
#pragma unroll
        for (int k0h = 0; k0h < 2; ++k0h) {
            half8 pf = *(half8*)&Pls[wave][l16 * PSTR + k0h*32 + quad*8];
            lacc = __builtin_amdgcn_mfma_f32_16x16x32_f16(ones, pf, lacc, 0, 0, 0);
#pragma unroll
            for (int t = 0; t < 4; ++t) {
                const int vrow = t*16 + l16;
                half8 vf = *(const half8*)&Vls[cur][vrow*64 + (((k0h*4 + quad) ^ (vrow & 7)) * 8)];
                o[t] = __builtin_amdgcn_mfma_f32_16x16x32_f16(vf, pf, o[t], 0, 0, 0);
            }
        }

        __syncthreads();
    }

    // ---- normalize + packed bf16 stores ----
    const float inv = 1.0f / lacc[0];
    const size_t rowp = (bS + myq) * D_MODEL + h*HD;
#pragma unroll
    for (int t = 0; t < 4; ++t) {
        union { short s4v[4]; int2 v; } u4;
#pragma unroll
        for (int r = 0; r < 4; ++r) u4.s4v[r] = f2bf(o[t][r] * inv);
        *(int2*)(ctx + rowp + t*16 + quad*4) = u4.v;
    }
#undef STAGE
}

// ---------------------------------------------------------------------------
extern "C" void kernel_launch(void* const* d_in, const int* in_sizes, int n_in,
                              void* d_out, int out_size, void* d_ws, size_t ws_size,
                              hipStream_t stream)
{
    int* flag = (int*)d_ws;
    short* xc = (short*)((char*)d_ws + 64);
    short* Wt = xc + NX;                 // 4 transposed weights q|k|v|o
    short* bc = Wt + 4 * NW;             // biases q|k|v|o
    short* qb = bc + 4 * D_MODEL;
    short* kb = qb + NX;
    _Float16* Vt = (_Float16*)(kb + NX); // [24][64][2048] f16
    short* cb = (short*)(Vt + NX);

    detect_and_bias<<<1, 256, 0, stream>>>((const short*)d_in[0], flag,
                                           d_in[2], d_in[4], d_in[6], d_in[8], bc);
    conv_x4<<<(int)(NX/4 + 255) / 256, 256, 0, stream>>>(d_in[0], xc, (int)(NX/4), flag);
    conv_wt<<<dim3(12, 12, 4), 256, 0, stream>>>(d_in[1], d_in[3], d_in[5], d_in[7], Wt, flag);

    qkv_gemm<<<dim3(NTOK/128, 2304/128), 256, 0, stream>>>(xc, Wt, bc, qb, kb, Vt);

    attn_mfma<<<dim3(SEQ/64, BATCH*NHEADS), 256, 0, stream>>>(qb, kb, Vt, cb);

    out_gemm<<<dim3(NTOK/64, D_MODEL/64), 256, 0, stream>>>(cb, Wt + 3*NW, bc + 3*D_MODEL, d_out, flag);
}

// Round 8
// 195.077 us; speedup vs baseline: 17.0753x; 1.0482x over previous
//
#include <hip/hip_runtime.h>
#include <hip/hip_bf16.h>
#include <hip/hip_fp16.h>

#define D_MODEL 768
#define NHEADS  12
#define HD      64
#define BATCH   2
#define SEQ     2048
#define NTOK    (BATCH*SEQ)   // 4096
#define NX      ((size_t)NTOK * D_MODEL)     // 3,145,728
#define NW      ((size_t)D_MODEL * D_MODEL)  // 589,824
#define SC_LOG2 0.18033688f   // (1/8) * log2(e), folded into Wq/bq

typedef __attribute__((ext_vector_type(8))) short    short8;
typedef __attribute__((ext_vector_type(8))) _Float16 half8;
typedef __attribute__((ext_vector_type(4))) float    f32x4;

__device__ __forceinline__ float bf2f(short s) {
    union { unsigned u; float f; } c;
    c.u = ((unsigned)(unsigned short)s) << 16;
    return c.f;
}
__device__ __forceinline__ short f2bf(float f) {
    __hip_bfloat16 h = __float2bfloat16(f);
    return *(short*)&h;
}

#ifdef __has_builtin
#if __has_builtin(__builtin_amdgcn_global_load_lds)
#define HAS_GLD 1
#endif
#endif
#ifdef HAS_GLD
#define GLD16(gp, lp) __builtin_amdgcn_global_load_lds( \
    (const __attribute__((address_space(1))) void*)(gp), \
    (__attribute__((address_space(3))) void*)(lp), 16, 0, 0)
#endif

// ---------------------------------------------------------------------------
// Fused conversion kernel (one launch): every block locally detects the input
// dtype from x's first 4096 halfwords (fp32 read as bf16 -> exponent fields
// >140 w.p. ~1), then converts its assigned slice.
//   blocks [0,3072):   x -> bf16 (int4-wide)
//   blocks [3072,3648): weight transpose+convert (Wq scaled by SC_LOG2)
//   block 3648:        biases (bq scaled) + persist flag for out_gemm
// ---------------------------------------------------------------------------
__global__ __launch_bounds__(256) void fused_conv(
        const void* __restrict__ xin,
        const void* __restrict__ w0, const void* __restrict__ w1,
        const void* __restrict__ w2, const void* __restrict__ w3,
        const void* __restrict__ b0, const void* __restrict__ b1,
        const void* __restrict__ b2, const void* __restrict__ b3,
        short* __restrict__ xc, short* __restrict__ wt,
        short* __restrict__ bc, int* __restrict__ flag)
{
    __shared__ int red[256];
    __shared__ float T[64][65];
    const int tid = threadIdx.x;
    const int F = blockIdx.x;

    // local dtype detect (all blocks)
    {
        const short* xs = (const short*)xin;
        int maxe = 0;
#pragma unroll
        for (int u = 0; u < 16; ++u) {
            int e = ((unsigned short)xs[tid * 16 + u] >> 7) & 0xFF;
            maxe = max(maxe, e);
        }
        red[tid] = maxe;
        __syncthreads();
        for (int s = 128; s > 0; s >>= 1) {
            if (tid < s) red[tid] = max(red[tid], red[tid + s]);
            __syncthreads();
        }
    }
    const bool isf = (red[0] > 140);

    if (F < 3072) {
        // ---- x conversion, 4-wide; 3072*256 == NX/4 exactly ----
        const int i = F * 256 + tid;
        if (isf) {
            float4 f = ((const float4*)xin)[i];
            short4 o = { f2bf(f.x), f2bf(f.y), f2bf(f.z), f2bf(f.w) };
            ((short4*)xc)[i] = o;
        } else {
            ((short4*)xc)[i] = ((const short4*)xin)[i];
        }
    } else if (F < 3648) {
        // ---- weight transpose+convert: Wt[n][k] = W[k][n] ----
        const int G = F - 3072;
        const int z = G / 144, rr = G % 144;
        const int k0 = (rr % 12) * 64, n0 = (rr / 12) * 64;
        const void* src = (z == 0) ? w0 : (z == 1) ? w1 : (z == 2) ? w2 : w3;
        const float sc = (z == 0) ? SC_LOG2 : 1.0f;
        const int la = tid & 15, lb = tid >> 4;
#pragma unroll
        for (int u = 0; u < 4; ++u) {
            const int kr = (lb & 3) + 4 * u + 16 * (lb >> 2);
            if (isf) {
                float4 f = *(const float4*)((const float*)src + (size_t)(k0 + kr) * D_MODEL + n0 + la * 4);
                T[kr][la*4+0] = f.x; T[kr][la*4+1] = f.y; T[kr][la*4+2] = f.z; T[kr][la*4+3] = f.w;
            } else {
                short4 s = *(const short4*)((const short*)src + (size_t)(k0 + kr) * D_MODEL + n0 + la * 4);
                T[kr][la*4+0] = bf2f(s.x); T[kr][la*4+1] = bf2f(s.y);
                T[kr][la*4+2] = bf2f(s.z); T[kr][la*4+3] = bf2f(s.w);
            }
        }
        __syncthreads();
#pragma unroll
        for (int u = 0; u < 4; ++u) {
            const int nr = (lb & 3) + 4 * u + 16 * (lb >> 2);
            short4 o = { f2bf(T[la*4+0][nr] * sc), f2bf(T[la*4+1][nr] * sc),
                         f2bf(T[la*4+2][nr] * sc), f2bf(T[la*4+3][nr] * sc) };
            *(short4*)(wt + (size_t)z * NW + (size_t)(n0 + nr) * D_MODEL + k0 + la * 4) = o;
        }
    } else {
        // ---- biases + flag ----
        if (tid == 0) *flag = isf ? 1 : 0;
        const void* srcs[4] = { b0, b1, b2, b3 };
        for (int z = 0; z < 4; ++z) {
            const float sc = (z == 0) ? SC_LOG2 : 1.0f;
            for (int i = tid; i < D_MODEL; i += 256) {
                float v = isf ? ((const float*)srcs[z])[i] : bf2f(((const short*)srcs[z])[i]);
                bc[z * D_MODEL + i] = f2bf(v * sc);
            }
        }
    }
}

// ---------------------------------------------------------------------------
// Fused QKV GEMM, double-buffered: OUT[4096][2304] = X @ [Wq|Wk|Wv] + bias.
// 128x128 tile, BK=32, GLD16 prefetch one k-step ahead.
// V segment -> Vt f16 [bh][dim][SEQ] via LDS transpose.
// ---------------------------------------------------------------------------
__global__ __launch_bounds__(256) void qkv_gemm(const short* __restrict__ X,
                                                const short* __restrict__ Wt,
                                                const short* __restrict__ bias,
                                                short* __restrict__ qb,
                                                short* __restrict__ kb,
                                                _Float16* __restrict__ Vt)
{
    __shared__ __align__(16) char shbuf[32768];
    short* Als = (short*)shbuf;              // [2][4096]
    short* Bls = (short*)(shbuf + 16384);    // [2][4096]
    _Float16* T = (_Float16*)shbuf;          // epilogue: 64*136 f16

    const int tid = threadIdx.x;
    const int wave = tid >> 6, lane = tid & 63;
    const int quad = lane >> 4, l16 = lane & 15;
    const int wm = wave & 1, wn = wave >> 1;
    const int m0 = blockIdx.x * 128;
    const int ng = blockIdx.y * 128;

    f32x4 acc[4][4];
#pragma unroll
    for (int nt = 0; nt < 4; ++nt) {
        const float bv = bf2f(bias[ng + wn*64 + nt*16 + l16]);
#pragma unroll
        for (int mt = 0; mt < 4; ++mt) acc[mt][nt] = (f32x4){bv, bv, bv, bv};
    }

    const int row = tid >> 2, ch = (tid & 3) * 8;
#ifdef HAS_GLD
#define QSTAGE(buf, k0) do { \
        GLD16(X  + (size_t)(m0 + row)      * D_MODEL + (k0) + ch, &Als[(buf)*4096 + tid*8]); \
        GLD16(X  + (size_t)(m0 + 64 + row) * D_MODEL + (k0) + ch, &Als[(buf)*4096 + 2048 + tid*8]); \
        GLD16(Wt + (size_t)(ng + row)      * D_MODEL + (k0) + ch, &Bls[(buf)*4096 + tid*8]); \
        GLD16(Wt + (size_t)(ng + 64 + row) * D_MODEL + (k0) + ch, &Bls[(buf)*4096 + 2048 + tid*8]); \
    } while (0)
#else
#define QSTAGE(buf, k0) do { \
        short8 r0 = *(const short8*)(X  + (size_t)(m0 + row)      * D_MODEL + (k0) + ch); \
        short8 r1 = *(const short8*)(X  + (size_t)(m0 + 64 + row) * D_MODEL + (k0) + ch); \
        short8 r2 = *(const short8*)(Wt + (size_t)(ng + row)      * D_MODEL + (k0) + ch); \
        short8 r3 = *(const short8*)(Wt + (size_t)(ng + 64 + row) * D_MODEL + (k0) + ch); \
        *(short8*)&Als[(buf)*4096 + tid*8] = r0;  *(short8*)&Als[(buf)*4096 + 2048 + tid*8] = r1; \
        *(short8*)&Bls[(buf)*4096 + tid*8] = r2;  *(short8*)&Bls[(buf)*4096 + 2048 + tid*8] = r3; \
    } while (0)
#endif

    QSTAGE(0, 0);
    __syncthreads();

    for (int ks = 0; ks < 24; ++ks) {
        const int cur = ks & 1;
        if (ks + 1 < 24) QSTAGE(cur ^ 1, (ks + 1) * 32);

        short8 a[4], b[4];
#pragma unroll
        for (int mt = 0; mt < 4; ++mt)
            a[mt] = *(const short8*)&Als[cur*4096 + (wm*64 + mt*16 + l16) * 32 + quad*8];
#pragma unroll
        for (int nt = 0; nt < 4; ++nt)
            b[nt] = *(const short8*)&Bls[cur*4096 + (wn*64 + nt*16 + l16) * 32 + quad*8];
#pragma unroll
        for (int mt = 0; mt < 4; ++mt)
#pragma unroll
        for (int nt = 0; nt < 4; ++nt)
            acc[mt][nt] = __builtin_amdgcn_mfma_f32_16x16x32_bf16(a[mt], b[nt], acc[mt][nt], 0, 0, 0);

        __syncthreads();
    }
#undef QSTAGE

    const int seg = blockIdx.y / 6;   // 0=q, 1=k, 2=v
    if (seg < 2) {
        short* out = seg ? kb : qb;
        const int nl = ng - seg * 768;
#pragma unroll
        for (int mt = 0; mt < 4; ++mt)
#pragma unroll
        for (int nt = 0; nt < 4; ++nt) {
            const int n = nl + wn*64 + nt*16 + l16;
#pragma unroll
            for (int r = 0; r < 4; ++r) {
                const int m = m0 + wm*64 + mt*16 + quad*4 + r;
                out[(size_t)m * D_MODEL + n] = f2bf(acc[mt][nt][r]);
            }
        }
    } else {
        // LDS-transpose epilogue: 2 passes of 64 dims x 128 tokens.
        const int batch = m0 >> 11, tokb = m0 & (SEQ - 1);
        for (int pass = 0; pass < 2; ++pass) {
            if (wn == pass) {
#pragma unroll
                for (int nt = 0; nt < 4; ++nt) {
                    const int dim_l = nt*16 + l16;
#pragma unroll
                    for (int mt = 0; mt < 4; ++mt) {
                        const int tok_l = wm*64 + mt*16 + quad*4;
                        union { _Float16 h4[4]; int2 v; } u;
#pragma unroll
                        for (int r = 0; r < 4; ++r) u.h4[r] = (_Float16)acc[mt][nt][r];
                        *(int2*)&T[dim_l * 136 + tok_l] = u.v;
                    }
                }
            }
            __syncthreads();
#pragma unroll
            for (int u = 0; u < 4; ++u) {
                const int slot = tid + u * 256;
                const int drow = slot >> 4, chk = slot & 15;
                int4 val = *(const int4*)&T[drow * 136 + chk * 8];
                const int dim_g = ng - 1536 + pass*64 + drow;
                const int h = dim_g >> 6, d = dim_g & 63;
                *(int4*)(Vt + ((size_t)(batch * NHEADS + h) * HD + d) * SEQ + tokb + chk*8) = val;
            }
            if (pass == 0) __syncthreads();
        }
    }
}

// ---------------------------------------------------------------------------
// Output projection, 64x64 tiles, double-buffered staging.
// ---------------------------------------------------------------------------
__global__ __launch_bounds__(256) void out_gemm(const short* __restrict__ X,
                                                const short* __restrict__ Wt,
                                                const short* __restrict__ bias,
                                                void* __restrict__ outv,
                                                const int* __restrict__ flag)
{
    __shared__ short Als[2][2048];
    __shared__ short Bls[2][2048];

    const int tid = threadIdx.x;
    const int wave = tid >> 6, lane = tid & 63;
    const int quad = lane >> 4, l16 = lane & 15;
    const int m0 = blockIdx.x * 64;
    const int n0 = blockIdx.y * 64;

    f32x4 acc[4];
#pragma unroll
    for (int nt = 0; nt < 4; ++nt) {
        const float bv = bf2f(bias[n0 + nt*16 + l16]);
        acc[nt] = (f32x4){bv, bv, bv, bv};
    }

    const int row = tid >> 2, ch = (tid & 3) * 8;
#ifdef HAS_GLD
#define OSTAGE(buf, k0) do { \
        GLD16(X  + (size_t)(m0 + row) * D_MODEL + (k0) + ch, &Als[buf][tid*8]); \
        GLD16(Wt + (size_t)(n0 + row) * D_MODEL + (k0) + ch, &Bls[buf][tid*8]); \
    } while (0)
#else
#define OSTAGE(buf, k0) do { \
        short8 r0 = *(const short8*)(X  + (size_t)(m0 + row) * D_MODEL + (k0) + ch); \
        short8 r1 = *(const short8*)(Wt + (size_t)(n0 + row) * D_MODEL + (k0) + ch); \
        *(short8*)&Als[buf][tid*8] = r0; \
        *(short8*)&Bls[buf][tid*8] = r1; \
    } while (0)
#endif

    OSTAGE(0, 0);
    __syncthreads();

    for (int ks = 0; ks < 24; ++ks) {
        const int cur = ks & 1;
        if (ks + 1 < 24) OSTAGE(cur ^ 1, (ks + 1) * 32);

        short8 a = *(const short8*)&Als[cur][(wave*16 + l16) * 32 + quad*8];
#pragma unroll
        for (int nt = 0; nt < 4; ++nt) {
            short8 b = *(const short8*)&Bls[cur][(nt*16 + l16) * 32 + quad*8];
            acc[nt] = __builtin_amdgcn_mfma_f32_16x16x32_bf16(a, b, acc[nt], 0, 0, 0);
        }
        __syncthreads();
    }
#undef OSTAGE

    const bool outf32 = (*flag != 0);
#pragma unroll
    for (int nt = 0; nt < 4; ++nt) {
        const int n = n0 + nt*16 + l16;
#pragma unroll
        for (int r = 0; r < 4; ++r) {
            const int m = m0 + wave*16 + quad*4 + r;
            const size_t idx = (size_t)m * D_MODEL + n;
            if (outf32) ((float*)outv)[idx] = acc[nt][r];
            else        ((short*)outv)[idx] = f2bf(acc[nt][r]);
        }
    }
}

// ---------------------------------------------------------------------------
// Flash attention with XCD-locality swizzle. Flat 768-block grid:
//   xcd = F&7, slot = F>>3, bh = xcd*3 + slot/32, qtile = slot%32
// -> all 32 q-tiles of one (b,h) on one XCD; per-XCD K+V set = 1.5 MB,
// L2-resident (was 12 MB thrash -> 53 MB HBM refetch).
// LDS = exactly 40 KB: K/V double-buffered swizzled, P-scratch XOR-swizzled.
// ---------------------------------------------------------------------------
__global__ __launch_bounds__(256) void attn_mfma(const short* __restrict__ q,
                                                 const short* __restrict__ k,
                                                 const _Float16* __restrict__ Vt,
                                                 short* __restrict__ ctx)
{
    __shared__ short    Kls[2][64 * 64];       // swizzled [key][chunk], 8 KB/buf
    __shared__ _Float16 Vls[2][64 * 64];       // swizzled [dim][chunk], 8 KB/buf
    __shared__ _Float16 Pls[4][16 * 64];       // per-wave, XOR-swizzled, 8 KB

    const int tid  = threadIdx.x;
    const int wave = tid >> 6, lane = tid & 63;
    const int quad = lane >> 4, l16 = lane & 15;

    const int F = blockIdx.x;
    const int xcd = F & 7, slot = F >> 3;
    const int bh = xcd * 3 + (slot >> 5);
    const int q0 = (slot & 31) * 64;
    const int b = bh / NHEADS, h = bh % NHEADS;
    const size_t bS = (size_t)b * SEQ;
    const int myq = q0 + wave * 16 + l16;

    short8 qf[2];
#pragma unroll
    for (int k0h = 0; k0h < 2; ++k0h)
        qf[k0h] = *(const short8*)(q + (bS + myq) * D_MODEL + h*HD + k0h*32 + quad*8);

    half8 ones;
#pragma unroll
    for (int j = 0; j < 8; ++j) ones[j] = (_Float16)1.0f;

    const int s0 = tid, s1 = tid + 256;
    const int kr0 = s0 >> 3, kc0 = (s0 & 7) ^ (kr0 & 7);
    const int kr1 = s1 >> 3, kc1 = (s1 & 7) ^ (kr1 & 7);
    const short*    kg0 = k  + (bS + kr0) * D_MODEL + h*HD + kc0*8;
    const short*    kg1 = k  + (bS + kr1) * D_MODEL + h*HD + kc1*8;
    const _Float16* vg0 = Vt + ((size_t)bh * HD + kr0) * SEQ + kc0*8;
    const _Float16* vg1 = Vt + ((size_t)bh * HD + kr1) * SEQ + kc1*8;

#ifdef HAS_GLD
#define STAGE(buf, j0) do { \
        GLD16(kg0 + (size_t)(j0) * D_MODEL, &Kls[buf][s0 * 8]); \
        GLD16(kg1 + (size_t)(j0) * D_MODEL, &Kls[buf][s1 * 8]); \
        GLD16(vg0 + (j0),                   &Vls[buf][s0 * 8]); \
        GLD16(vg1 + (j0),                   &Vls[buf][s1 * 8]); \
    } while (0)
#else
#define STAGE(buf, j0) do { \
        short8 a_ = *(const short8*)(kg0 + (size_t)(j0) * D_MODEL); \
        short8 b_ = *(const short8*)(kg1 + (size_t)(j0) * D_MODEL); \
        half8  c_ = *(const half8*)(vg0 + (j0)); \
        half8  d_ = *(const half8*)(vg1 + (j0)); \
        *(short8*)&Kls[buf][s0 * 8] = a_;  *(short8*)&Kls[buf][s1 * 8] = b_; \
        *(half8*)&Vls[buf][s0 * 8] = c_;   *(half8*)&Vls[buf][s1 * 8] = d_; \
    } while (0)
#endif

    float m_ = -1e30f;
    f32x4 lacc = (f32x4){0.f, 0.f, 0.f, 0.f};
    f32x4 o[4];
#pragma unroll
    for (int t = 0; t < 4; ++t) o[t] = (f32x4){0.f, 0.f, 0.f, 0.f};

    STAGE(0, 0);
    __syncthreads();

    for (int jt = 0; jt < SEQ / 64; ++jt) {
        const int cur = jt & 1;
        if (jt + 1 < SEQ / 64) STAGE(cur ^ 1, (jt + 1) * 64);

        // ---- S^T = K * Q^T (exp2-domain logits) ----
        f32x4 s4[4];
#pragma unroll
        for (int t = 0; t < 4; ++t) s4[t] = (f32x4){0.f, 0.f, 0.f, 0.f};
#pragma unroll
        for (int k0h = 0; k0h < 2; ++k0h)
#pragma unroll
        for (int t = 0; t < 4; ++t) {
            const int krow = t*16 + l16;
            short8 kf = *(const short8*)&Kls[cur][krow*64 + (((k0h*4 + quad) ^ (krow & 7)) * 8)];
            s4[t] = __builtin_amdgcn_mfma_f32_16x16x32_bf16(kf, qf[k0h], s4[t], 0, 0, 0);
        }

        // ---- wave-shared online max; rescale only on increase ----
        float mx = s4[0][0];
#pragma unroll
        for (int t = 0; t < 4; ++t)
#pragma unroll
        for (int r = 0; r < 4; ++r) mx = fmaxf(mx, s4[t][r]);
#pragma unroll
        for (int d = 1; d < 64; d <<= 1) mx = fmaxf(mx, __shfl_xor(mx, d));
        const float mn = fmaxf(m_, mx);
        if (__builtin_amdgcn_readfirstlane((int)(mn > m_))) {
            const float al = exp2f(m_ - mn);
#pragma unroll
            for (int t = 0; t < 4; ++t) {
                o[t][0] *= al; o[t][1] *= al; o[t][2] *= al; o[t][3] *= al;
            }
            lacc[0] *= al; lacc[1] *= al; lacc[2] *= al; lacc[3] *= al;
            m_ = mn;
        }

        // ---- P = exp2(S - m), f16, XOR-swizzled per-wave LDS ----
#pragma unroll
        for (int t = 0; t < 4; ++t) {
            union { _Float16 h4[4]; int2 v; } u4;
#pragma unroll
            for (int r = 0; r < 4; ++r) u4.h4[r] = (_Float16)exp2f(s4[t][r] - mn);
            const int c = (t*2 + (quad >> 1)) ^ (l16 & 7);
            *(int2*)&Pls[wave][l16*64 + c*8 + (quad & 1)*4] = u4.v;
        }

        // ---- O^T += V^T * P^T ; l += ones * P^T (MFMA pipe) ----
#pragma unroll
        for (int k0h = 0; k0h < 2; ++k0h) {
            const int pc = (k0h*4 + quad) ^ (l16 & 7);
            half8 pf = *(half8*)&Pls[wave][l16*64 + pc*8];
            lacc = __builtin_amdgcn_mfma_f32_16x16x32_f16(ones, pf, lacc, 0, 0, 0);
#pragma unroll
            for (int t = 0; t < 4; ++t) {
                const int vrow = t*16 + l16;
                half8 vf = *(const half8*)&Vls[cur][vrow*64 + (((k0h*4 + quad) ^ (vrow & 7)) * 8)];
                o[t] = __builtin_amdgcn_mfma_f32_16x16x32_f16(vf, pf, o[t], 0, 0, 0);
            }
        }

        __syncthreads();
    }

    // ---- normalize + packed bf16 stores ----
    const float inv = 1.0f / lacc[0];
    const size_t rowp = (bS + myq) * D_MODEL + h*HD;
#pragma unroll
    for (int t = 0; t < 4; ++t) {
        union { short s4v[4]; int2 v; } u4;
#pragma unroll
        for (int r = 0; r < 4; ++r) u4.s4v[r] = f2bf(o[t][r] * inv);
        *(int2*)(ctx + rowp + t*16 + quad*4) = u4.v;
    }
#undef STAGE
}

// ---------------------------------------------------------------------------
extern "C" void kernel_launch(void* const* d_in, const int* in_sizes, int n_in,
                              void* d_out, int out_size, void* d_ws, size_t ws_size,
                              hipStream_t stream)
{
    int* flag = (int*)d_ws;
    short* xc = (short*)((char*)d_ws + 64);
    short* Wt = xc + NX;                 // 4 transposed weights q|k|v|o
    short* bc = Wt + 4 * NW;             // biases q|k|v|o
    short* qb = bc + 4 * D_MODEL;
    short* kb = qb + NX;
    _Float16* Vt = (_Float16*)(kb + NX); // [24][64][2048] f16
    short* cb = (short*)(Vt + NX);

    fused_conv<<<3649, 256, 0, stream>>>(d_in[0],
                                         d_in[1], d_in[3], d_in[5], d_in[7],
                                         d_in[2], d_in[4], d_in[6], d_in[8],
                                         xc, Wt, bc, flag);

    qkv_gemm<<<dim3(NTOK/128, 2304/128), 256, 0, stream>>>(xc, Wt, bc, qb, kb, Vt);

    attn_mfma<<<768, 256, 0, stream>>>(qb, kb, Vt, cb);

    out_gemm<<<dim3(NTOK/64, D_MODEL/64), 256, 0, stream>>>(cb, Wt + 3*NW, bc + 3*D_MODEL, d_out, flag);
}